// Round 1
// 870.571 us; speedup vs baseline: 1.3627x; 1.3627x over previous
//
#include <hip/hip_runtime.h>
#include <cstdint>

// ElasticMHA on MI355X (gfx950). Inputs/outputs FLOAT32; internals bf16 MFMA.
// R7: barrier-free attention. K and V^T MFMA B-fragments loaded directly from
//     global (L2-resident; V pre-transposed by vtr_kernel, pad rows zeroed);
//     pvhb bias tables computed by MFMA against a precomputed bf16 combined
//     K-table; rel-V value table precomputed transposed in global. All LDS in
//     attn is per-wave private -> zero __syncthreads in the kernel; XCD-chunked
//     block swizzle for K/V L2 locality. GEMMs unchanged (m97 staging).

typedef unsigned short u16;
typedef unsigned int   u32;
typedef __attribute__((ext_vector_type(8))) __bf16 bf16x8;
typedef __attribute__((ext_vector_type(4))) float  f32x4;

#define B_   32
#define L_   577
#define D_   768
#define H_   12
#define HD_  64
#define LP_  640            // padded rows per (b,h): 10 Q-tiles of 64
#define M_   (B_*L_)        // 18464
#define SCALE_ 0.125f

__device__ __forceinline__ float b2f(u16 u){ u32 x = ((u32)u) << 16; float f; __builtin_memcpy(&f,&x,4); return f; }
__device__ __forceinline__ u16 f2b(float f){ u32 x; __builtin_memcpy(&x,&f,4); u32 r = (x + 0x7FFFu + ((x>>16)&1u)) >> 16; return (u16)r; }

__device__ __forceinline__ f32x4 mfma_bf16(bf16x8 a, bf16x8 b, f32x4 c){
  return __builtin_amdgcn_mfma_f32_16x16x32_bf16(a, b, c, 0, 0, 0);
}

// async global->LDS, 16B/lane; LDS dest = wave-uniform base + lane*16 (m97/m104)
__device__ __forceinline__ void async16(const void* g, void* l){
  __builtin_amdgcn_global_load_lds(
    (const __attribute__((address_space(1))) void*)g,
    (__attribute__((address_space(3))) void*)l,
    16, 0, 0);
}

__device__ __forceinline__ void lds_fence(){
  asm volatile("s_waitcnt lgkmcnt(0)" ::: "memory");
}

// ---------------- indicator fragments for histogram MFMA ----------------
// ind[jt][nt][lane][idx]: B-fragment element Ind[k = (lane>>4)*8+idx][n = nt*16+(lane&15)]
// for j = jt*32+k. bins: n<25 -> gv (g==n), 25<=n<50 -> gh (cb==n-25), else 0.
__global__ __launch_bounds__(256) void ind_setup(u16* __restrict__ ind)
{
  int jt = blockIdx.x;
  int t  = threadIdx.x;
  int nt = t >> 6, lane = t & 63;
  int qq = lane >> 4, cc = lane & 15;
  int n = nt*16 + cc;
  u16 vals[8];
  #pragma unroll
  for (int idx = 0; idx < 8; ++idx){
    int j = jt*32 + qq*8 + idx;
    int bv, bhh;
    if (j == 0){ bv = 24; bhh = 24; }
    else { int jj = j-1; bv = jj/24; if (bv > 23) bv = 23; bhh = jj - (jj/24)*24; }
    bool one = (n < 25) ? (bv == n) : ((n < 50) ? (bhh == n-25) : false);
    vals[idx] = one ? (u16)0x3F80 : (u16)0;
  }
  *(uint4*)&ind[(size_t)((jt*4 + nt)*64 + lane)*8] = *(uint4*)vals;
}

// ---------------- combined rel tables, bf16 ----------------
// tabK [bin(64)][d(64)]  : bin<30 -> tvk[bin], bin<60 -> thk[bin-30], else 0
// tabVT[d(64)][bin(64)]  : bin<30 -> tvv[bin][d], bin<60 -> thv[bin-30][d], else 0
__global__ __launch_bounds__(256) void tab_setup(
    const float* __restrict__ tvk, const float* __restrict__ thk,
    const float* __restrict__ tvv, const float* __restrict__ thv,
    u16* __restrict__ tabK, u16* __restrict__ tabVT)
{
  int i = blockIdx.x*256 + threadIdx.x;
  if (i >= 64*64) return;
  int r = i >> 6, col = i & 63;
  float kv = 0.f;
  if (r < 30)      kv = tvk[r*HD_ + col];
  else if (r < 60) kv = thk[(r-30)*HD_ + col];
  tabK[i] = f2b(kv);
  float vv = 0.f;                    // tabVT: r = d, col = bin
  if (col < 30)      vv = tvv[col*HD_ + r];
  else if (col < 60) vv = thv[(col-30)*HD_ + r];
  tabVT[i] = f2b(vv);
}

// ---------------- q/k/v f32 -> bf16 cvt prepass ----------------
__global__ __launch_bounds__(256) void cvt3_bf16(
    const float* __restrict__ q, const float* __restrict__ k, const float* __restrict__ v,
    u16* __restrict__ dq, u16* __restrict__ dk, u16* __restrict__ dv)
{
  int z = blockIdx.y;
  const float* s = (z==0)?q:(z==1)?k:v;
  u16*         d = (z==0)?dq:(z==1)?dk:dv;
  int i = blockIdx.x*256 + threadIdx.x;          // uint4 (8 elem) index
  if (i >= (M_*D_)/8) return;
  const float4* s4 = (const float4*)s;
  float4 a = s4[2*i], b = s4[2*i+1];
  uint4 o;
  o.x = (u32)f2b(a.x) | ((u32)f2b(a.y)<<16);
  o.y = (u32)f2b(a.z) | ((u32)f2b(a.w)<<16);
  o.z = (u32)f2b(b.x) | ((u32)f2b(b.y)<<16);
  o.w = (u32)f2b(b.z) | ((u32)f2b(b.w)<<16);
  ((uint4*)d)[i] = o;
}

// ---------------- weight transpose+cvt: WT[n][k] = bf16(W[k][n]) ----------------
__global__ __launch_bounds__(256) void transpose768(
    const float* __restrict__ W0, const float* __restrict__ W1,
    const float* __restrict__ W2, const float* __restrict__ W3,
    u16* __restrict__ T0, u16* __restrict__ T1, u16* __restrict__ T2, u16* __restrict__ T3)
{
  __shared__ float t[32][33];
  int z = blockIdx.z;
  const float* W = (z==0)?W0:(z==1)?W1:(z==2)?W2:W3;
  u16*         T = (z==0)?T0:(z==1)?T1:(z==2)?T2:T3;
  int kb = blockIdx.x*32, nb = blockIdx.y*32;
  int tx = threadIdx.x & 31, ty = threadIdx.x >> 5;   // 32 x 8
  #pragma unroll
  for (int r=0;r<32;r+=8) t[ty+r][tx] = W[(size_t)(kb+ty+r)*768 + nb+tx];
  __syncthreads();
  #pragma unroll
  for (int r=0;r<32;r+=8) T[(size_t)(nb+ty+r)*768 + kb+tx] = f2b(t[tx][ty+r]);
}

// ---------------- V head-layout -> V^T [b,h,d(64)][j(LP)], pad rows zeroed ----------------
__global__ __launch_bounds__(256) void vtr_kernel(
    const u16* __restrict__ vh, u16* __restrict__ vhT)
{
  __shared__ __align__(16) u16 t[64][72];
  int ll0 = blockIdx.x * 64;
  size_t bhs = (size_t)(blockIdx.z*H_ + blockIdx.y) * LP_ * HD_;
  const u16* src = vh + bhs;
  u16* dst = vhT + bhs;
  int tid = threadIdx.x;
  #pragma unroll
  for (int it=0; it<2; ++it){
    int idx = it*256 + tid;                // 0..511
    int row = idx >> 3, ch = (idx & 7)*8;
    uint4 d4; d4.x=0u; d4.y=0u; d4.z=0u; d4.w=0u;
    if (ll0 + row < L_) d4 = *(const uint4*)(src + (size_t)(ll0+row)*HD_ + ch);
    *(uint4*)&t[row][ch] = d4;
  }
  __syncthreads();
  #pragma unroll
  for (int it=0; it<2; ++it){
    int idx = it*256 + tid;
    int dd = idx >> 3, l8 = (idx & 7)*8;
    u16 vals[8];
    #pragma unroll
    for (int e=0;e<8;++e) vals[e] = t[l8+e][dd];
    *(uint4*)(dst + (size_t)dd*LP_ + ll0 + l8) = *(uint4*)vals;
  }
}

// ---------------- 128x128 MFMA GEMM, m97 staging, XCD swizzle ----------------
// mode 0..2: A = bf16 [M,768], Dst = bf16 head layout [B,H,LP,64] (+bias)
// mode 3   : A = bf16 oh head layout, Dst = f32 out [M,768] (+bias+residual)
__global__ __launch_bounds__(256) void gemm_kernel(
    const u16* __restrict__ A, const u16* __restrict__ BT,
    const float* __restrict__ bias, const float* __restrict__ resid,
    void* __restrict__ Dstv, int mode)
{
  __shared__ __align__(16) u16 AsL[128*32];
  __shared__ __align__(16) u16 BsL[128*32];
  const int blk = blockIdx.x;
  const int x = blk & 7, g = blk >> 3;       // XCD-slot, work id
  const int n0 = (g % 6) * 128;
  const int m_idx = (g / 6) * 8 + x;
  if (m_idx >= 145) return;
  const int m0 = m_idx * 128;

  const int tid = threadIdx.x;
  const int w = tid>>6, lane = tid&63, q = lane>>4, c = lane&15;
  const int wr = w>>1, wc = w&1;

  f32x4 acc[4][4];
  #pragma unroll
  for (int ai=0;ai<4;++ai)
    #pragma unroll
    for (int bi=0;bi<4;++bi){ f32x4 z = {0.f,0.f,0.f,0.f}; acc[ai][bi] = z; }

  for (int k0 = 0; k0 < 768; k0 += 32){
    __syncthreads();
    #pragma unroll
    for (int t2 = 0; t2 < 2; ++t2){
      int idx = t2*256 + tid;
      int row = idx >> 2, ch = idx & 3;
      int mrow = m0 + row; if (mrow > M_-1) mrow = M_-1;
      const u16* srcA;
      if (mode < 3) srcA = A + (size_t)mrow*768 + k0 + ch*8;
      else {
        int bb = mrow / L_, ll = mrow - bb*L_;
        int hh = k0 >> 6, dd = (k0 & 63) + ch*8;
        srcA = A + (((size_t)(bb*H_ + hh)*LP_ + ll) << 6) + dd;
      }
      async16(srcA, (char*)AsL + (size_t)(t2*256 + w*64)*16);
      async16(BT + (size_t)(n0 + row)*768 + k0 + ch*8, (char*)BsL + (size_t)(t2*256 + w*64)*16);
    }
    __syncthreads();

    bf16x8 af[4], bf2[4];
    #pragma unroll
    for (int ai=0;ai<4;++ai) af[ai]  = *(const bf16x8*)&AsL[(wr*64 + ai*16 + c)*32 + q*8];
    #pragma unroll
    for (int bi=0;bi<4;++bi) bf2[bi] = *(const bf16x8*)&BsL[(wc*64 + bi*16 + c)*32 + q*8];
    #pragma unroll
    for (int ai=0;ai<4;++ai)
      #pragma unroll
      for (int bi=0;bi<4;++bi)
        acc[ai][bi] = mfma_bf16(af[ai], bf2[bi], acc[ai][bi]);
  }

  // epilogue: C layout row = q*4+reg, col = lane&15 (m89)
  #pragma unroll
  for (int ai=0;ai<4;++ai){
    #pragma unroll
    for (int r2=0;r2<4;++r2){
      int mrow = m0 + wr*64 + ai*16 + q*4 + r2;
      if (mrow >= M_) continue;
      int bb = mrow / L_;
      int ll = mrow - bb*L_;
      #pragma unroll
      for (int bi=0;bi<4;++bi){
        int col = n0 + wc*64 + bi*16 + c;
        float vv = acc[ai][bi][r2] + bias[col];
        if (mode < 3){
          int hh = col >> 6, dd = col & 63;
          ((u16*)Dstv)[(((size_t)(bb*H_ + hh)*LP_ + ll) << 6) + dd] = f2b(vv);
        } else {
          size_t o2 = (size_t)mrow*768 + col;
          ((float*)Dstv)[o2] = vv + resid[o2];
        }
      }
    }
  }
}

// ---------------- fused attention, barrier-free ----------------
// 256 thr (4 waves), each wave owns 16 Q rows of one (b,h); 19 x 32-col j-tiles.
// All LDS per-wave private (6720 B/wave): [gvh f32 16x52 | Ps u16 16x40 | pvhb u16 16x66],
// Wm u16 16x72 overlays Ps+pvhb after the main loop. Zero __syncthreads.
__global__ __launch_bounds__(256) void attn_kernel(
    const u16* __restrict__ qh, const u16* __restrict__ kh, const u16* __restrict__ vhT,
    const u16* __restrict__ tabK, const u16* __restrict__ tabVT,
    const u16* __restrict__ ind,
    u16* __restrict__ oh)
{
  __shared__ __align__(16) char sb[4*6720];
  const int tid = threadIdx.x;
  const int w = tid>>6, lane = tid&63, q = lane>>4, c = lane&15;
  char* wb = sb + w*6720;
  float* gvh  = (float*)wb;              // 3328 B : [16][52] f32
  u16*   Ps_w = (u16*)(wb + 3328);       // 1280 B : [16][40] u16
  u16*   pvhb = (u16*)(wb + 4608);       // 2112 B : [16][66] u16

  // XCD-chunked work decode: 8 XCDs x 480 contiguous ids; qt fastest within chunk
  const int id = blockIdx.x;
  const int lin = (id & 7)*480 + (id >> 3);
  const int qt = lin % 10;
  const int hb = lin / 10;
  const int h = hb % 12, b = hb / 12;

  const int i0 = qt * 64;
  const size_t bh = (size_t)(b*H_ + h) * LP_ * HD_;
  const u16* qh_b = qh + bh;
  const u16* kh_b = kh + bh;
  const u16* vT_b = vhT + bh;            // [64][LP_]

  // Q fragments (A layout: m=lane&15, k=q*8+j)
  bf16x8 aq0 = *(const bf16x8*)(qh_b + (size_t)(i0 + w*16 + c)*HD_ + q*8);
  bf16x8 aq1 = *(const bf16x8*)(qh_b + (size_t)(i0 + w*16 + c)*HD_ + 32 + q*8);

  // pvhb[16 rows][bins 0..59] = Q . tabK^T via MFMA (replaces scalar dotqt pass)
  #pragma unroll
  for (int nt=0; nt<4; ++nt){
    bf16x8 tb0 = *(const bf16x8*)(tabK + (size_t)(nt*16+c)*64 + q*8);
    bf16x8 tb1 = *(const bf16x8*)(tabK + (size_t)(nt*16+c)*64 + 32 + q*8);
    f32x4 s = {0.f,0.f,0.f,0.f};
    s = mfma_bf16(aq0, tb0, s);
    s = mfma_bf16(aq1, tb1, s);
    int bin = nt*16 + c;
    if (bin < 60){
      #pragma unroll
      for (int r=0;r<4;++r) pvhb[(q*4+r)*66 + bin] = f2b(s[r]);
    }
  }
  lds_fence();

  // per-lane row constants (C layout rows: q*4+r)
  int rv_[4], cv_[4], ig_[4];
  #pragma unroll
  for (int r=0;r<4;++r){
    int ig = i0 + w*16 + q*4 + r;
    ig_[r] = ig;
    int ii = ig > 0 ? ig - 1 : 0;
    int dv24 = ii / 24;
    rv_[r] = dv24;
    cv_[r] = ii - dv24*24;
  }
  float pv0[4], ph0[4];
  #pragma unroll
  for (int r=0;r<4;++r){
    int lr = q*4 + r;
    pv0[r] = b2f(pvhb[lr*66 + 0]);
    ph0[r] = b2f(pvhb[lr*66 + 30]);
  }

  f32x4 o4[4], hist[4];
  #pragma unroll
  for (int nt=0;nt<4;++nt){ f32x4 z = {0.f,0.f,0.f,0.f}; o4[nt] = z; hist[nt] = z; }

  for (int jt = 0; jt < 19; ++jt){
    int j0 = jt * 32;
    uint4 bi_raw[4];
    #pragma unroll
    for (int nt=0;nt<4;++nt) bi_raw[nt] = ((const uint4*)ind)[(jt*4 + nt)*64 + lane];

    lds_fence();   // order prev iter's ap read vs this iter's Ps writes (TBAA)
    #pragma unroll
    for (int sub=0; sub<2; ++sub){
      // K B-fragment direct from global (L1/L2-resident)
      const u16* kr = kh_b + (size_t)(j0 + sub*16 + c)*HD_;
      bf16x8 bk0 = *(const bf16x8*)(kr + q*8);
      bf16x8 bk1 = *(const bf16x8*)(kr + 32 + q*8);
      f32x4 s4 = {0.f,0.f,0.f,0.f};
      s4 = mfma_bf16(aq0, bk0, s4);
      s4 = mfma_bf16(aq1, bk1, s4);

      int jbase = j0 + sub*16;
      int j  = jbase + c;
      bool jv = (j < L_);
      int jj = j - 1;
      int gR  = (j==0) ? 24 : (jj/24);  if (gR > 23 && j != 0) gR = 23;   // gv bin
      int cbR = (j==0) ? 24 : (jj - (jj/24)*24);                          // gh bin
      int sga = (jbase <= 1) ? 0 : ((jbase-1)/24); if (sga > 23) sga = 23;
      int sgb = (jbase + 14) / 24;                 if (sgb > 23) sgb = 23;

      #pragma unroll
      for (int r=0;r<4;++r){
        int lr = q*4 + r;
        int dvlo = sga - rv_[r]; dvlo = dvlo < -14 ? -14 : (dvlo > 14 ? 14 : dvlo);
        int dvhi = sgb - rv_[r]; dvhi = dvhi < -14 ? -14 : (dvhi > 14 ? 14 : dvhi);
        float bvlo = b2f(pvhb[lr*66 + dvlo + 15]);
        float bvhi = b2f(pvhb[lr*66 + dvhi + 15]);
        float bv = (gR == sgb) ? bvhi : bvlo;
        int dh = cbR - cv_[r]; dh = dh < -14 ? -14 : (dh > 14 ? 14 : dh);
        float bhh = b2f(pvhb[lr*66 + dh + 45]);
        bool cls = (j == 0) || (ig_[r] == 0);
        float bias = (cls ? pv0[r] : bv) + (cls ? ph0[r] : bhh);
        float s = s4[r]*SCALE_ + bias;
        s = fminf(fmaxf(s, -80.f), 30.f);           // NaN-proof clamp
        float p = jv ? __expf(s) : 0.f;             // no-max softmax
        Ps_w[lr*40 + sub*16 + c] = f2b(p);
      }
    }
    // P round-trip through per-wave LDS (m120); fence stops TBAA reordering
    lds_fence();
    bf16x8 ap = *(const bf16x8*)(Ps_w + c*40 + q*8);
    #pragma unroll
    for (int nt=0;nt<4;++nt){
      // V^T B-fragment direct from global (pre-transposed, pad rows zeroed)
      bf16x8 bv2 = *(const bf16x8*)(vT_b + (size_t)(nt*16+c)*LP_ + j0 + q*8);
      o4[nt] = mfma_bf16(ap, bv2, o4[nt]);
      bf16x8 bI = *(const bf16x8*)&bi_raw[nt];
      hist[nt] = mfma_bf16(ap, bI, hist[nt]);
    }
  }

  // histogram C-regs -> gvh: local row=q*4+r, bin=nt*16+c (each cell one writer)
  #pragma unroll
  for (int nt=0;nt<4;++nt){
    int bin = nt*16 + c;
    if (bin < 50){
      #pragma unroll
      for (int r=0;r<4;++r)
        gvh[(size_t)(q*4 + r)*52 + bin] = hist[nt][r];
    }
  }
  lds_fence();

  // fold histograms into table-space weights Wm[16][72] bf16 (overlay Ps+pvhb)
  u16* Wm = (u16*)(wb + 3328);
  for (int o = lane; o < 16*72; o += 64) Wm[o] = 0;
  lds_fence();
  if (lane < 16){
    int ig = i0 + w*16 + lane;
    const float* gv = gvh + (size_t)lane*52;
    u16* wrp = Wm + lane*72;
    if (ig == 0){
      float sv=0.f, sh=0.f;
      for (int g2=0; g2<25; ++g2){ sv += gv[g2]; sh += gv[25+g2]; }
      wrp[0] = f2b(sv); wrp[30] = f2b(sh);
    } else {
      int rr = (ig-1)/24, cc2 = (ig-1) - ((ig-1)/24)*24;
      wrp[0]  = f2b(gv[24]);     // CLS -> table idx 0
      wrp[30] = f2b(gv[49]);
      for (int t=1; t<30; ++t){
        float sv = 0.f, sh = 0.f;
        if (t == 1){
          for (int g2=0; g2 <= rr-14  && g2 < 24; ++g2) sv += gv[g2];
          for (int c2=0; c2 <= cc2-14 && c2 < 24; ++c2) sh += gv[25+c2];
        } else if (t == 29){
          for (int g2 = (rr+14  < 0 ? 0 : rr+14 ); g2 < 24; ++g2) sv += gv[g2];
          for (int c2 = (cc2+14 < 0 ? 0 : cc2+14); c2 < 24; ++c2) sh += gv[25+c2];
        } else {
          int g2 = rr  + t - 15; if (g2 >= 0 && g2 < 24) sv = gv[g2];
          int c2 = cc2 + t - 15; if (c2 >= 0 && c2 < 24) sh = gv[25+c2];
        }
        wrp[t] = f2b(sv); wrp[30+t] = f2b(sh);
      }
    }
  }
  lds_fence();

  // rel-V term: o += W(16x64) @ TabV(64x64), TabV^T from global
  bf16x8 aw0 = *(const bf16x8*)(Wm + c*72 + q*8);
  bf16x8 aw1 = *(const bf16x8*)(Wm + c*72 + 32 + q*8);
  #pragma unroll
  for (int nt=0;nt<4;++nt){
    bf16x8 bt0 = *(const bf16x8*)(tabVT + (size_t)(nt*16+c)*64 + q*8);
    bf16x8 bt1 = *(const bf16x8*)(tabVT + (size_t)(nt*16+c)*64 + 32 + q*8);
    o4[nt] = mfma_bf16(aw0, bt0, o4[nt]);
    o4[nt] = mfma_bf16(aw1, bt1, o4[nt]);
  }

  // softmax denominator from histogram row sums (bins 0..24) + store
  u16* oh_b = oh + bh;
  #pragma unroll
  for (int r=0;r<4;++r){
    if (ig_[r] < L_){
      const float* gr = gvh + (size_t)(q*4 + r)*52;
      f32x4 a0 = *(const f32x4*)(gr);
      f32x4 a1 = *(const f32x4*)(gr+4);
      f32x4 a2 = *(const f32x4*)(gr+8);
      f32x4 a3 = *(const f32x4*)(gr+12);
      f32x4 a4 = *(const f32x4*)(gr+16);
      f32x4 a5 = *(const f32x4*)(gr+20);
      float lsum = (a0[0]+a0[1]+a0[2]+a0[3]) + (a1[0]+a1[1]+a1[2]+a1[3])
                 + (a2[0]+a2[1]+a2[2]+a2[3]) + (a3[0]+a3[1]+a3[2]+a3[3])
                 + (a4[0]+a4[1]+a4[2]+a4[3]) + (a5[0]+a5[1]+a5[2]+a5[3]) + gr[24];
      float inv = 1.f / lsum;
      #pragma unroll
      for (int nt=0;nt<4;++nt)
        oh_b[(size_t)ig_[r]*HD_ + nt*16 + c] = f2b(o4[nt][r] * inv);
    }
  }
}

// ---------------- launch ----------------
extern "C" void kernel_launch(void* const* d_in, const int* in_sizes, int n_in,
                              void* d_out, int out_size, void* d_ws, size_t ws_size,
                              hipStream_t stream)
{
  (void)in_sizes; (void)n_in; (void)out_size; (void)ws_size;
  const float* q_   = (const float*)d_in[0];
  const float* k_   = (const float*)d_in[1];
  const float* v_   = (const float*)d_in[2];
  const float* Wq_  = (const float*)d_in[3];
  const float* bq_  = (const float*)d_in[4];
  const float* Wk_  = (const float*)d_in[5];
  const float* bk_  = (const float*)d_in[6];
  const float* Wv_  = (const float*)d_in[7];
  const float* bv_  = (const float*)d_in[8];
  const float* Wp_  = (const float*)d_in[9];
  const float* bp_  = (const float*)d_in[10];
  const float* tvk_ = (const float*)d_in[11];
  const float* thk_ = (const float*)d_in[12];
  const float* tvv_ = (const float*)d_in[13];
  const float* thv_ = (const float*)d_in[14];

  char* ws = (char*)d_ws;
  const size_t szHead = (size_t)B_*H_*LP_*HD_*2;   // 31,457,280 B
  const size_t szQKV  = (size_t)M_*D_*2;           // 28,360,704 B
  u16* qh   = (u16*)(ws);
  u16* kh   = (u16*)(ws + szHead);
  u16* vh   = (u16*)(ws + 2*szHead);
  u16* oh   = (u16*)(ws + 3*szHead);   // doubles as q_bf before attn
  u16* q_bf = oh;
  u16* k_bf = (u16*)(ws + 4*szHead);
  u16* v_bf = (u16*)(ws + 4*szHead + szQKV);
  u16* vhT  = k_bf;                    // overlay: k_bf/v_bf dead after their GEMMs
  u16* WqT  = (u16*)(ws + 4*szHead + 2*szQKV);
  u16* WkT  = WqT + 768*768;
  u16* WvT  = WkT + 768*768;
  u16* WpT  = WvT + 768*768;
  u16* ind  = WpT + 768*768;           // 77,824 B
  u16* tabK  = ind + 19*4*64*8;        // 8,192 B
  u16* tabVT = tabK + 64*64;           // 8,192 B
  // total ~187.4 MB

  ind_setup<<<19, 256, 0, stream>>>(ind);
  tab_setup<<<16, 256, 0, stream>>>(tvk_, thk_, tvv_, thv_, tabK, tabVT);
  transpose768<<<dim3(24,24,4), 256, 0, stream>>>(Wq_, Wk_, Wv_, Wp_, WqT, WkT, WvT, WpT);
  cvt3_bf16<<<dim3((M_*D_/8 + 255)/256, 3), 256, 0, stream>>>(q_, k_, v_, q_bf, k_bf, v_bf);
  gemm_kernel<<<912, 256, 0, stream>>>(q_bf, WqT, bq_, nullptr, qh, 0);
  gemm_kernel<<<912, 256, 0, stream>>>(k_bf, WkT, bk_, nullptr, kh, 1);
  gemm_kernel<<<912, 256, 0, stream>>>(v_bf, WvT, bv_, nullptr, vh, 2);
  vtr_kernel<<<dim3(10,12,32), 256, 0, stream>>>(vh, vhT);
  attn_kernel<<<3840, 256, 0, stream>>>(qh, kh, vhT, tabK, tabVT, ind, oh);
  gemm_kernel<<<912, 256, 0, stream>>>(oh, WpT, bp_, q_, d_out, 3);
}

// Round 2
// 868.509 us; speedup vs baseline: 1.3659x; 1.0024x over previous
//
#include <hip/hip_runtime.h>
#include <cstdint>

// ElasticMHA on MI355X (gfx950). Inputs/outputs FLOAT32; internals bf16 MFMA.
// R8: attn bias path via separable per-row gather tables bias_t[row][50]
//     (built once per block from pvhb) -> inner loop is 2 LDS gathers + fma +
//     exp per entry (was ~30 VALU + 5 gathers). V/ind fragments prefetched at
//     j-tile top; s_setprio(1) around MFMA clusters. Barrier-free as R7.
//     GEMMs unchanged (m97 staging + XCD swizzle).

typedef unsigned short u16;
typedef unsigned int   u32;
typedef __attribute__((ext_vector_type(8))) __bf16 bf16x8;
typedef __attribute__((ext_vector_type(4))) float  f32x4;

#define B_   32
#define L_   577
#define D_   768
#define H_   12
#define HD_  64
#define LP_  640            // padded rows per (b,h): 10 Q-tiles of 64
#define M_   (B_*L_)        // 18464
#define SCALE_ 0.125f

__device__ __forceinline__ float b2f(u16 u){ u32 x = ((u32)u) << 16; float f; __builtin_memcpy(&f,&x,4); return f; }
__device__ __forceinline__ u16 f2b(float f){ u32 x; __builtin_memcpy(&x,&f,4); u32 r = (x + 0x7FFFu + ((x>>16)&1u)) >> 16; return (u16)r; }

__device__ __forceinline__ f32x4 mfma_bf16(bf16x8 a, bf16x8 b, f32x4 c){
  return __builtin_amdgcn_mfma_f32_16x16x32_bf16(a, b, c, 0, 0, 0);
}

// async global->LDS, 16B/lane; LDS dest = wave-uniform base + lane*16 (m97/m104)
__device__ __forceinline__ void async16(const void* g, void* l){
  __builtin_amdgcn_global_load_lds(
    (const __attribute__((address_space(1))) void*)g,
    (__attribute__((address_space(3))) void*)l,
    16, 0, 0);
}

__device__ __forceinline__ void lds_fence(){
  asm volatile("s_waitcnt lgkmcnt(0)" ::: "memory");
}

// ---------------- indicator fragments for histogram MFMA ----------------
// ind[jt][nt][lane][idx]: B-fragment element Ind[k = (lane>>4)*8+idx][n = nt*16+(lane&15)]
// for j = jt*32+k. bins: n<25 -> gv (g==n), 25<=n<50 -> gh (cb==n-25), else 0.
__global__ __launch_bounds__(256) void ind_setup(u16* __restrict__ ind)
{
  int jt = blockIdx.x;
  int t  = threadIdx.x;
  int nt = t >> 6, lane = t & 63;
  int qq = lane >> 4, cc = lane & 15;
  int n = nt*16 + cc;
  u16 vals[8];
  #pragma unroll
  for (int idx = 0; idx < 8; ++idx){
    int j = jt*32 + qq*8 + idx;
    int bv, bhh;
    if (j == 0){ bv = 24; bhh = 24; }
    else { int jj = j-1; bv = jj/24; if (bv > 23) bv = 23; bhh = jj - (jj/24)*24; }
    bool one = (n < 25) ? (bv == n) : ((n < 50) ? (bhh == n-25) : false);
    vals[idx] = one ? (u16)0x3F80 : (u16)0;
  }
  *(uint4*)&ind[(size_t)((jt*4 + nt)*64 + lane)*8] = *(uint4*)vals;
}

// ---------------- combined rel tables, bf16 ----------------
// tabK [bin(64)][d(64)]  : bin<30 -> tvk[bin], bin<60 -> thk[bin-30], else 0
// tabVT[d(64)][bin(64)]  : bin<30 -> tvv[bin][d], bin<60 -> thv[bin-30][d], else 0
__global__ __launch_bounds__(256) void tab_setup(
    const float* __restrict__ tvk, const float* __restrict__ thk,
    const float* __restrict__ tvv, const float* __restrict__ thv,
    u16* __restrict__ tabK, u16* __restrict__ tabVT)
{
  int i = blockIdx.x*256 + threadIdx.x;
  if (i >= 64*64) return;
  int r = i >> 6, col = i & 63;
  float kv = 0.f;
  if (r < 30)      kv = tvk[r*HD_ + col];
  else if (r < 60) kv = thk[(r-30)*HD_ + col];
  tabK[i] = f2b(kv);
  float vv = 0.f;                    // tabVT: r = d, col = bin
  if (col < 30)      vv = tvv[col*HD_ + r];
  else if (col < 60) vv = thv[(col-30)*HD_ + r];
  tabVT[i] = f2b(vv);
}

// ---------------- q/k/v f32 -> bf16 cvt prepass ----------------
__global__ __launch_bounds__(256) void cvt3_bf16(
    const float* __restrict__ q, const float* __restrict__ k, const float* __restrict__ v,
    u16* __restrict__ dq, u16* __restrict__ dk, u16* __restrict__ dv)
{
  int z = blockIdx.y;
  const float* s = (z==0)?q:(z==1)?k:v;
  u16*         d = (z==0)?dq:(z==1)?dk:dv;
  int i = blockIdx.x*256 + threadIdx.x;          // uint4 (8 elem) index
  if (i >= (M_*D_)/8) return;
  const float4* s4 = (const float4*)s;
  float4 a = s4[2*i], b = s4[2*i+1];
  uint4 o;
  o.x = (u32)f2b(a.x) | ((u32)f2b(a.y)<<16);
  o.y = (u32)f2b(a.z) | ((u32)f2b(a.w)<<16);
  o.z = (u32)f2b(b.x) | ((u32)f2b(b.y)<<16);
  o.w = (u32)f2b(b.z) | ((u32)f2b(b.w)<<16);
  ((uint4*)d)[i] = o;
}

// ---------------- weight transpose+cvt: WT[n][k] = bf16(W[k][n]) ----------------
__global__ __launch_bounds__(256) void transpose768(
    const float* __restrict__ W0, const float* __restrict__ W1,
    const float* __restrict__ W2, const float* __restrict__ W3,
    u16* __restrict__ T0, u16* __restrict__ T1, u16* __restrict__ T2, u16* __restrict__ T3)
{
  __shared__ float t[32][33];
  int z = blockIdx.z;
  const float* W = (z==0)?W0:(z==1)?W1:(z==2)?W2:W3;
  u16*         T = (z==0)?T0:(z==1)?T1:(z==2)?T2:T3;
  int kb = blockIdx.x*32, nb = blockIdx.y*32;
  int tx = threadIdx.x & 31, ty = threadIdx.x >> 5;   // 32 x 8
  #pragma unroll
  for (int r=0;r<32;r+=8) t[ty+r][tx] = W[(size_t)(kb+ty+r)*768 + nb+tx];
  __syncthreads();
  #pragma unroll
  for (int r=0;r<32;r+=8) T[(size_t)(nb+ty+r)*768 + kb+tx] = f2b(t[tx][ty+r]);
}

// ---------------- V head-layout -> V^T [b,h,d(64)][j(LP)], pad rows zeroed ----------------
__global__ __launch_bounds__(256) void vtr_kernel(
    const u16* __restrict__ vh, u16* __restrict__ vhT)
{
  __shared__ __align__(16) u16 t[64][72];
  int ll0 = blockIdx.x * 64;
  size_t bhs = (size_t)(blockIdx.z*H_ + blockIdx.y) * LP_ * HD_;
  const u16* src = vh + bhs;
  u16* dst = vhT + bhs;
  int tid = threadIdx.x;
  #pragma unroll
  for (int it=0; it<2; ++it){
    int idx = it*256 + tid;                // 0..511
    int row = idx >> 3, ch = (idx & 7)*8;
    uint4 d4; d4.x=0u; d4.y=0u; d4.z=0u; d4.w=0u;
    if (ll0 + row < L_) d4 = *(const uint4*)(src + (size_t)(ll0+row)*HD_ + ch);
    *(uint4*)&t[row][ch] = d4;
  }
  __syncthreads();
  #pragma unroll
  for (int it=0; it<2; ++it){
    int idx = it*256 + tid;
    int dd = idx >> 3, l8 = (idx & 7)*8;
    u16 vals[8];
    #pragma unroll
    for (int e=0;e<8;++e) vals[e] = t[l8+e][dd];
    *(uint4*)(dst + (size_t)dd*LP_ + ll0 + l8) = *(uint4*)vals;
  }
}

// ---------------- 128x128 MFMA GEMM, m97 staging, XCD swizzle ----------------
// mode 0..2: A = bf16 [M,768], Dst = bf16 head layout [B,H,LP,64] (+bias)
// mode 3   : A = bf16 oh head layout, Dst = f32 out [M,768] (+bias+residual)
__global__ __launch_bounds__(256) void gemm_kernel(
    const u16* __restrict__ A, const u16* __restrict__ BT,
    const float* __restrict__ bias, const float* __restrict__ resid,
    void* __restrict__ Dstv, int mode)
{
  __shared__ __align__(16) u16 AsL[128*32];
  __shared__ __align__(16) u16 BsL[128*32];
  const int blk = blockIdx.x;
  const int x = blk & 7, g = blk >> 3;       // XCD-slot, work id
  const int n0 = (g % 6) * 128;
  const int m_idx = (g / 6) * 8 + x;
  if (m_idx >= 145) return;
  const int m0 = m_idx * 128;

  const int tid = threadIdx.x;
  const int w = tid>>6, lane = tid&63, q = lane>>4, c = lane&15;
  const int wr = w>>1, wc = w&1;

  f32x4 acc[4][4];
  #pragma unroll
  for (int ai=0;ai<4;++ai)
    #pragma unroll
    for (int bi=0;bi<4;++bi){ f32x4 z = {0.f,0.f,0.f,0.f}; acc[ai][bi] = z; }

  for (int k0 = 0; k0 < 768; k0 += 32){
    __syncthreads();
    #pragma unroll
    for (int t2 = 0; t2 < 2; ++t2){
      int idx = t2*256 + tid;
      int row = idx >> 2, ch = idx & 3;
      int mrow = m0 + row; if (mrow > M_-1) mrow = M_-1;
      const u16* srcA;
      if (mode < 3) srcA = A + (size_t)mrow*768 + k0 + ch*8;
      else {
        int bb = mrow / L_, ll = mrow - bb*L_;
        int hh = k0 >> 6, dd = (k0 & 63) + ch*8;
        srcA = A + (((size_t)(bb*H_ + hh)*LP_ + ll) << 6) + dd;
      }
      async16(srcA, (char*)AsL + (size_t)(t2*256 + w*64)*16);
      async16(BT + (size_t)(n0 + row)*768 + k0 + ch*8, (char*)BsL + (size_t)(t2*256 + w*64)*16);
    }
    __syncthreads();

    bf16x8 af[4], bf2[4];
    #pragma unroll
    for (int ai=0;ai<4;++ai) af[ai]  = *(const bf16x8*)&AsL[(wr*64 + ai*16 + c)*32 + q*8];
    #pragma unroll
    for (int bi=0;bi<4;++bi) bf2[bi] = *(const bf16x8*)&BsL[(wc*64 + bi*16 + c)*32 + q*8];
    #pragma unroll
    for (int ai=0;ai<4;++ai)
      #pragma unroll
      for (int bi=0;bi<4;++bi)
        acc[ai][bi] = mfma_bf16(af[ai], bf2[bi], acc[ai][bi]);
  }

  // epilogue: C layout row = q*4+reg, col = lane&15 (m89)
  #pragma unroll
  for (int ai=0;ai<4;++ai){
    #pragma unroll
    for (int r2=0;r2<4;++r2){
      int mrow = m0 + wr*64 + ai*16 + q*4 + r2;
      if (mrow >= M_) continue;
      int bb = mrow / L_;
      int ll = mrow - bb*L_;
      #pragma unroll
      for (int bi=0;bi<4;++bi){
        int col = n0 + wc*64 + bi*16 + c;
        float vv = acc[ai][bi][r2] + bias[col];
        if (mode < 3){
          int hh = col >> 6, dd = col & 63;
          ((u16*)Dstv)[(((size_t)(bb*H_ + hh)*LP_ + ll) << 6) + dd] = f2b(vv);
        } else {
          size_t o2 = (size_t)mrow*768 + col;
          ((float*)Dstv)[o2] = vv + resid[o2];
        }
      }
    }
  }
}

// ---------------- fused attention, barrier-free ----------------
// 256 thr (4 waves), each wave owns 16 Q rows of one (b,h); 19 x 32-col j-tiles.
// Per-wave LDS (6272 B): [0,3328) pvhb u16[16][66] (setup) -> gvh f32[16][52] (end);
// [3328,4608) Ps u16[16][40]; [4608,6272) bias_t u16[16][52];
// Wm u16[16][72] overlays Ps+bias_t after the loop. Zero __syncthreads.
__global__ __launch_bounds__(256) void attn_kernel(
    const u16* __restrict__ qh, const u16* __restrict__ kh, const u16* __restrict__ vhT,
    const u16* __restrict__ tabK, const u16* __restrict__ tabVT,
    const u16* __restrict__ ind,
    u16* __restrict__ oh)
{
  __shared__ __align__(16) char sb[4*6272];
  const int tid = threadIdx.x;
  const int w = tid>>6, lane = tid&63, q = lane>>4, c = lane&15;
  char* wb = sb + w*6272;
  float* gvh   = (float*)wb;             // [16][52] f32 (after loop)
  u16*   pvhb  = (u16*)wb;               // [16][66] u16 (setup only; overlays gvh)
  u16*   Ps_w  = (u16*)(wb + 3328);      // [16][40] u16
  u16*   bias_t= (u16*)(wb + 4608);      // [16][52] u16: [g 0..24 | cb 0..24], CLS at 24/49

  // XCD-chunked work decode: 8 XCDs x 480 contiguous ids; qt fastest within chunk
  const int id = blockIdx.x;
  const int lin = (id & 7)*480 + (id >> 3);
  const int qt = lin % 10;
  const int hb = lin / 10;
  const int h = hb % 12, b = hb / 12;

  const int i0 = qt * 64;
  const size_t bh = (size_t)(b*H_ + h) * LP_ * HD_;
  const u16* qh_b = qh + bh;
  const u16* kh_b = kh + bh;
  const u16* vT_b = vhT + bh;            // [64][LP_]

  // Q fragments (A layout: m=lane&15, k=q*8+j)
  bf16x8 aq0 = *(const bf16x8*)(qh_b + (size_t)(i0 + w*16 + c)*HD_ + q*8);
  bf16x8 aq1 = *(const bf16x8*)(qh_b + (size_t)(i0 + w*16 + c)*HD_ + 32 + q*8);

  // pvhb[16 rows][bins 0..59] = Q . tabK^T via MFMA
  #pragma unroll
  for (int nt=0; nt<4; ++nt){
    bf16x8 tb0 = *(const bf16x8*)(tabK + (size_t)(nt*16+c)*64 + q*8);
    bf16x8 tb1 = *(const bf16x8*)(tabK + (size_t)(nt*16+c)*64 + 32 + q*8);
    f32x4 s = {0.f,0.f,0.f,0.f};
    s = mfma_bf16(aq0, tb0, s);
    s = mfma_bf16(aq1, tb1, s);
    int bin = nt*16 + c;
    if (bin < 60){
      #pragma unroll
      for (int r=0;r<4;++r) pvhb[(q*4+r)*66 + bin] = f2b(s[r]);
    }
  }
  lds_fence();

  // build separable gather tables: bias_t[row][g] = pv_row(g), bias_t[row][25+cb] = ph_row(cb)
  // g/cb==24 is the CLS slot; rows with ig==0 get CLS everywhere (i==0 -> all-CLS bias).
  for (int o = lane; o < 16*50; o += 64){
    int row = o / 50, t = o - (o/50)*50;
    int ig = i0 + w*16 + row;
    const u16* src = pvhb + row*66;
    u16 val;
    if (ig == 0){
      val = src[t < 25 ? 0 : 30];
    } else {
      int im1 = ig - 1;
      int rr = im1 / 24, cc2 = im1 - (im1/24)*24;
      if (t < 25){
        if (t == 24) val = src[0];
        else { int d = t - rr;  d = d < -14 ? -14 : (d > 14 ? 14 : d); val = src[15 + d]; }
      } else {
        int cb = t - 25;
        if (cb == 24) val = src[30];
        else { int d = cb - cc2; d = d < -14 ? -14 : (d > 14 ? 14 : d); val = src[45 + d]; }
      }
    }
    bias_t[row*52 + t] = val;
  }
  lds_fence();

  // per-lane row ids for the output guard
  int ig_[4];
  #pragma unroll
  for (int r=0;r<4;++r) ig_[r] = i0 + w*16 + q*4 + r;

  f32x4 o4[4], hist[4];
  #pragma unroll
  for (int nt=0;nt<4;++nt){ f32x4 z = {0.f,0.f,0.f,0.f}; o4[nt] = z; hist[nt] = z; }

  const u16* btr = bias_t + (q*4)*52;

  for (int jt = 0; jt < 19; ++jt){
    int j0 = jt * 32;
    lds_fence();   // order prev iter's Ps read vs this iter's Ps writes (TBAA)

    // early independent global loads: V^T fragments + indicator fragments
    bf16x8 bvf[4];
    #pragma unroll
    for (int nt=0;nt<4;++nt)
      bvf[nt] = *(const bf16x8*)(vT_b + (size_t)(nt*16+c)*LP_ + j0 + q*8);
    uint4 bi_raw[4];
    #pragma unroll
    for (int nt=0;nt<4;++nt) bi_raw[nt] = ((const uint4*)ind)[(jt*4 + nt)*64 + lane];

    #pragma unroll
    for (int sub=0; sub<2; ++sub){
      const u16* kr = kh_b + (size_t)(j0 + sub*16 + c)*HD_;
      bf16x8 bk0 = *(const bf16x8*)(kr + q*8);
      bf16x8 bk1 = *(const bf16x8*)(kr + 32 + q*8);
      f32x4 s4 = {0.f,0.f,0.f,0.f};
      __builtin_amdgcn_s_setprio(1);
      s4 = mfma_bf16(aq0, bk0, s4);
      s4 = mfma_bf16(aq1, bk1, s4);
      __builtin_amdgcn_s_setprio(0);

      int j  = j0 + sub*16 + c;
      bool jv = (j < L_);
      int jj = j - 1;
      int q24 = jj / 24;
      int gR  = (j==0) ? 24 : (q24 > 23 ? 23 : q24);
      int cbR = (j==0) ? 24 : (jj - q24*24);

      #pragma unroll
      for (int r=0;r<4;++r){
        float bias = b2f(btr[r*52 + gR]) + b2f(btr[r*52 + 25 + cbR]);
        float s = fmaf(s4[r], SCALE_, bias);
        s = fminf(fmaxf(s, -80.f), 30.f);           // NaN-proof clamp
        float p = jv ? __expf(s) : 0.f;             // no-max softmax
        __bf16 pb = (__bf16)p;
        u16 pu; __builtin_memcpy(&pu, &pb, 2);
        Ps_w[(q*4+r)*40 + sub*16 + c] = pu;
      }
    }
    // P round-trip through per-wave LDS (m120); fence stops TBAA reordering
    lds_fence();
    bf16x8 ap = *(const bf16x8*)(Ps_w + c*40 + q*8);
    __builtin_amdgcn_s_setprio(1);
    #pragma unroll
    for (int nt=0;nt<4;++nt){
      o4[nt] = mfma_bf16(ap, bvf[nt], o4[nt]);
      bf16x8 bI = *(const bf16x8*)&bi_raw[nt];
      hist[nt] = mfma_bf16(ap, bI, hist[nt]);
    }
    __builtin_amdgcn_s_setprio(0);
  }

  lds_fence();   // drain final Ps/bias_t reads before overlaying with gvh/Wm

  // histogram C-regs -> gvh: local row=q*4+r, bin=nt*16+c (each cell one writer)
  #pragma unroll
  for (int nt=0;nt<4;++nt){
    int bin = nt*16 + c;
    if (bin < 50){
      #pragma unroll
      for (int r=0;r<4;++r)
        gvh[(size_t)(q*4 + r)*52 + bin] = hist[nt][r];
    }
  }
  lds_fence();

  // fold histograms into table-space weights Wm[16][72] bf16 (overlay Ps+bias_t)
  u16* Wm = (u16*)(wb + 3328);
  for (int o = lane; o < 16*72; o += 64) Wm[o] = 0;
  lds_fence();
  if (lane < 16){
    int ig = i0 + w*16 + lane;
    const float* gv = gvh + (size_t)lane*52;
    u16* wrp = Wm + lane*72;
    if (ig == 0){
      float sv=0.f, sh=0.f;
      for (int g2=0; g2<25; ++g2){ sv += gv[g2]; sh += gv[25+g2]; }
      wrp[0] = f2b(sv); wrp[30] = f2b(sh);
    } else {
      int rr = (ig-1)/24, cc2 = (ig-1) - ((ig-1)/24)*24;
      wrp[0]  = f2b(gv[24]);     // CLS -> table idx 0
      wrp[30] = f2b(gv[49]);
      for (int t=1; t<30; ++t){
        float sv = 0.f, sh = 0.f;
        if (t == 1){
          for (int g2=0; g2 <= rr-14  && g2 < 24; ++g2) sv += gv[g2];
          for (int c2=0; c2 <= cc2-14 && c2 < 24; ++c2) sh += gv[25+c2];
        } else if (t == 29){
          for (int g2 = (rr+14  < 0 ? 0 : rr+14 ); g2 < 24; ++g2) sv += gv[g2];
          for (int c2 = (cc2+14 < 0 ? 0 : cc2+14); c2 < 24; ++c2) sh += gv[25+c2];
        } else {
          int g2 = rr  + t - 15; if (g2 >= 0 && g2 < 24) sv = gv[g2];
          int c2 = cc2 + t - 15; if (c2 >= 0 && c2 < 24) sh = gv[25+c2];
        }
        wrp[t] = f2b(sv); wrp[30+t] = f2b(sh);
      }
    }
  }
  lds_fence();

  // rel-V term: o += W(16x64) @ TabV(64x64), TabV^T from global
  bf16x8 aw0 = *(const bf16x8*)(Wm + c*72 + q*8);
  bf16x8 aw1 = *(const bf16x8*)(Wm + c*72 + 32 + q*8);
  __builtin_amdgcn_s_setprio(1);
  #pragma unroll
  for (int nt=0;nt<4;++nt){
    bf16x8 bt0 = *(const bf16x8*)(tabVT + (size_t)(nt*16+c)*64 + q*8);
    bf16x8 bt1 = *(const bf16x8*)(tabVT + (size_t)(nt*16+c)*64 + 32 + q*8);
    o4[nt] = mfma_bf16(aw0, bt0, o4[nt]);
    o4[nt] = mfma_bf16(aw1, bt1, o4[nt]);
  }
  __builtin_amdgcn_s_setprio(0);

  // softmax denominator from histogram row sums (bins 0..24) + store
  u16* oh_b = oh + bh;
  #pragma unroll
  for (int r=0;r<4;++r){
    if (ig_[r] < L_){
      const float* gr = gvh + (size_t)(q*4 + r)*52;
      f32x4 a0 = *(const f32x4*)(gr);
      f32x4 a1 = *(const f32x4*)(gr+4);
      f32x4 a2 = *(const f32x4*)(gr+8);
      f32x4 a3 = *(const f32x4*)(gr+12);
      f32x4 a4 = *(const f32x4*)(gr+16);
      f32x4 a5 = *(const f32x4*)(gr+20);
      float lsum = (a0[0]+a0[1]+a0[2]+a0[3]) + (a1[0]+a1[1]+a1[2]+a1[3])
                 + (a2[0]+a2[1]+a2[2]+a2[3]) + (a3[0]+a3[1]+a3[2]+a3[3])
                 + (a4[0]+a4[1]+a4[2]+a4[3]) + (a5[0]+a5[1]+a5[2]+a5[3]) + gr[24];
      float inv = 1.f / lsum;
      #pragma unroll
      for (int nt=0;nt<4;++nt)
        oh_b[(size_t)ig_[r]*HD_ + nt*16 + c] = f2b(o4[nt][r] * inv);
    }
  }
}

// ---------------- launch ----------------
extern "C" void kernel_launch(void* const* d_in, const int* in_sizes, int n_in,
                              void* d_out, int out_size, void* d_ws, size_t ws_size,
                              hipStream_t stream)
{
  (void)in_sizes; (void)n_in; (void)out_size; (void)ws_size;
  const float* q_   = (const float*)d_in[0];
  const float* k_   = (const float*)d_in[1];
  const float* v_   = (const float*)d_in[2];
  const float* Wq_  = (const float*)d_in[3];
  const float* bq_  = (const float*)d_in[4];
  const float* Wk_  = (const float*)d_in[5];
  const float* bk_  = (const float*)d_in[6];
  const float* Wv_  = (const float*)d_in[7];
  const float* bv_  = (const float*)d_in[8];
  const float* Wp_  = (const float*)d_in[9];
  const float* bp_  = (const float*)d_in[10];
  const float* tvk_ = (const float*)d_in[11];
  const float* thk_ = (const float*)d_in[12];
  const float* tvv_ = (const float*)d_in[13];
  const float* thv_ = (const float*)d_in[14];

  char* ws = (char*)d_ws;
  const size_t szHead = (size_t)B_*H_*LP_*HD_*2;   // 31,457,280 B
  const size_t szQKV  = (size_t)M_*D_*2;           // 28,360,704 B
  u16* qh   = (u16*)(ws);
  u16* kh   = (u16*)(ws + szHead);
  u16* vh   = (u16*)(ws + 2*szHead);
  u16* oh   = (u16*)(ws + 3*szHead);   // doubles as q_bf before attn
  u16* q_bf = oh;
  u16* k_bf = (u16*)(ws + 4*szHead);
  u16* v_bf = (u16*)(ws + 4*szHead + szQKV);
  u16* vhT  = k_bf;                    // overlay: k_bf/v_bf dead after their GEMMs
  u16* WqT  = (u16*)(ws + 4*szHead + 2*szQKV);
  u16* WkT  = WqT + 768*768;
  u16* WvT  = WkT + 768*768;
  u16* WpT  = WvT + 768*768;
  u16* ind  = WpT + 768*768;           // 77,824 B
  u16* tabK  = ind + 19*4*64*8;        // 8,192 B
  u16* tabVT = tabK + 64*64;           // 8,192 B
  // total ~187.4 MB

  ind_setup<<<19, 256, 0, stream>>>(ind);
  tab_setup<<<16, 256, 0, stream>>>(tvk_, thk_, tvv_, thv_, tabK, tabVT);
  transpose768<<<dim3(24,24,4), 256, 0, stream>>>(Wq_, Wk_, Wv_, Wp_, WqT, WkT, WvT, WpT);
  cvt3_bf16<<<dim3((M_*D_/8 + 255)/256, 3), 256, 0, stream>>>(q_, k_, v_, q_bf, k_bf, v_bf);
  gemm_kernel<<<912, 256, 0, stream>>>(q_bf, WqT, bq_, nullptr, qh, 0);
  gemm_kernel<<<912, 256, 0, stream>>>(k_bf, WkT, bk_, nullptr, kh, 1);
  gemm_kernel<<<912, 256, 0, stream>>>(v_bf, WvT, bv_, nullptr, vh, 2);
  vtr_kernel<<<dim3(10,12,32), 256, 0, stream>>>(vh, vhT);
  attn_kernel<<<3840, 256, 0, stream>>>(qh, kh, vhT, tabK, tabVT, ind, oh);
  gemm_kernel<<<912, 256, 0, stream>>>(oh, WpT, bp_, q_, d_out, 3);
}

// Round 3
// 792.502 us; speedup vs baseline: 1.4969x; 1.0959x over previous
//
#include <hip/hip_runtime.h>
#include <cstdint>

// ElasticMHA on MI355X (gfx950). Inputs/outputs FLOAT32; internals bf16 MFMA.
// R9: software-pipelined attention j-loop (double-buffered Ps: softmax for
//     tile t+1 overlaps PV MFMAs of tile t; LDS round-trip latency hidden),
//     compiler-barrier instead of lgkmcnt(0) in the hot loop (same-wave DS
//     ops are in-order), per-wave LDS shrunk to 5632 B via pvhb/Ps overlay,
//     QKV GEMMs merged into one 2736-block launch (tail amortization).
//     Bias gather tables (R8) + barrier-free structure (R7) retained.

typedef unsigned short u16;
typedef unsigned int   u32;
typedef __attribute__((ext_vector_type(8))) __bf16 bf16x8;
typedef __attribute__((ext_vector_type(4))) float  f32x4;

#define B_   32
#define L_   577
#define D_   768
#define H_   12
#define HD_  64
#define LP_  640            // padded rows per (b,h): 10 Q-tiles of 64
#define M_   (B_*L_)        // 18464
#define SCALE_ 0.125f

__device__ __forceinline__ float b2f(u16 u){ u32 x = ((u32)u) << 16; float f; __builtin_memcpy(&f,&x,4); return f; }
__device__ __forceinline__ u16 f2b(float f){ u32 x; __builtin_memcpy(&x,&f,4); u32 r = (x + 0x7FFFu + ((x>>16)&1u)) >> 16; return (u16)r; }

__device__ __forceinline__ f32x4 mfma_bf16(bf16x8 a, bf16x8 b, f32x4 c){
  return __builtin_amdgcn_mfma_f32_16x16x32_bf16(a, b, c, 0, 0, 0);
}

// async global->LDS, 16B/lane; LDS dest = wave-uniform base + lane*16 (m97/m104)
__device__ __forceinline__ void async16(const void* g, void* l){
  __builtin_amdgcn_global_load_lds(
    (const __attribute__((address_space(1))) void*)g,
    (__attribute__((address_space(3))) void*)l,
    16, 0, 0);
}

__device__ __forceinline__ void lds_fence(){
  asm volatile("s_waitcnt lgkmcnt(0)" ::: "memory");
}
// compiler-only ordering (same-wave LDS ops execute in order on HW)
__device__ __forceinline__ void cbar(){
  asm volatile("" ::: "memory");
}

// ---------------- indicator fragments for histogram MFMA ----------------
// ind[jt][nt][lane][idx]: B-fragment element Ind[k = (lane>>4)*8+idx][n = nt*16+(lane&15)]
// for j = jt*32+k. bins: n<25 -> gv (g==n), 25<=n<50 -> gh (cb==n-25), else 0.
__global__ __launch_bounds__(256) void ind_setup(u16* __restrict__ ind)
{
  int jt = blockIdx.x;
  int t  = threadIdx.x;
  int nt = t >> 6, lane = t & 63;
  int qq = lane >> 4, cc = lane & 15;
  int n = nt*16 + cc;
  u16 vals[8];
  #pragma unroll
  for (int idx = 0; idx < 8; ++idx){
    int j = jt*32 + qq*8 + idx;
    int bv, bhh;
    if (j == 0){ bv = 24; bhh = 24; }
    else { int jj = j-1; bv = jj/24; if (bv > 23) bv = 23; bhh = jj - (jj/24)*24; }
    bool one = (n < 25) ? (bv == n) : ((n < 50) ? (bhh == n-25) : false);
    vals[idx] = one ? (u16)0x3F80 : (u16)0;
  }
  *(uint4*)&ind[(size_t)((jt*4 + nt)*64 + lane)*8] = *(uint4*)vals;
}

// ---------------- combined rel tables, bf16 ----------------
// tabK [bin(64)][d(64)]  : bin<30 -> tvk[bin], bin<60 -> thk[bin-30], else 0
// tabVT[d(64)][bin(64)]  : bin<30 -> tvv[bin][d], bin<60 -> thv[bin-30][d], else 0
__global__ __launch_bounds__(256) void tab_setup(
    const float* __restrict__ tvk, const float* __restrict__ thk,
    const float* __restrict__ tvv, const float* __restrict__ thv,
    u16* __restrict__ tabK, u16* __restrict__ tabVT)
{
  int i = blockIdx.x*256 + threadIdx.x;
  if (i >= 64*64) return;
  int r = i >> 6, col = i & 63;
  float kv = 0.f;
  if (r < 30)      kv = tvk[r*HD_ + col];
  else if (r < 60) kv = thk[(r-30)*HD_ + col];
  tabK[i] = f2b(kv);
  float vv = 0.f;                    // tabVT: r = d, col = bin
  if (col < 30)      vv = tvv[col*HD_ + r];
  else if (col < 60) vv = thv[(col-30)*HD_ + r];
  tabVT[i] = f2b(vv);
}

// ---------------- q/k/v f32 -> bf16 cvt prepass ----------------
__global__ __launch_bounds__(256) void cvt3_bf16(
    const float* __restrict__ q, const float* __restrict__ k, const float* __restrict__ v,
    u16* __restrict__ dq, u16* __restrict__ dk, u16* __restrict__ dv)
{
  int z = blockIdx.y;
  const float* s = (z==0)?q:(z==1)?k:v;
  u16*         d = (z==0)?dq:(z==1)?dk:dv;
  int i = blockIdx.x*256 + threadIdx.x;          // uint4 (8 elem) index
  if (i >= (M_*D_)/8) return;
  const float4* s4 = (const float4*)s;
  float4 a = s4[2*i], b = s4[2*i+1];
  uint4 o;
  o.x = (u32)f2b(a.x) | ((u32)f2b(a.y)<<16);
  o.y = (u32)f2b(a.z) | ((u32)f2b(a.w)<<16);
  o.z = (u32)f2b(b.x) | ((u32)f2b(b.y)<<16);
  o.w = (u32)f2b(b.z) | ((u32)f2b(b.w)<<16);
  ((uint4*)d)[i] = o;
}

// ---------------- weight transpose+cvt: WT[n][k] = bf16(W[k][n]) ----------------
__global__ __launch_bounds__(256) void transpose768(
    const float* __restrict__ W0, const float* __restrict__ W1,
    const float* __restrict__ W2, const float* __restrict__ W3,
    u16* __restrict__ T0, u16* __restrict__ T1, u16* __restrict__ T2, u16* __restrict__ T3)
{
  __shared__ float t[32][33];
  int z = blockIdx.z;
  const float* W = (z==0)?W0:(z==1)?W1:(z==2)?W2:W3;
  u16*         T = (z==0)?T0:(z==1)?T1:(z==2)?T2:T3;
  int kb = blockIdx.x*32, nb = blockIdx.y*32;
  int tx = threadIdx.x & 31, ty = threadIdx.x >> 5;   // 32 x 8
  #pragma unroll
  for (int r=0;r<32;r+=8) t[ty+r][tx] = W[(size_t)(kb+ty+r)*768 + nb+tx];
  __syncthreads();
  #pragma unroll
  for (int r=0;r<32;r+=8) T[(size_t)(nb+ty+r)*768 + kb+tx] = f2b(t[tx][ty+r]);
}

// ---------------- V head-layout -> V^T [b,h,d(64)][j(LP)], pad rows zeroed ----------------
__global__ __launch_bounds__(256) void vtr_kernel(
    const u16* __restrict__ vh, u16* __restrict__ vhT)
{
  __shared__ __align__(16) u16 t[64][72];
  int ll0 = blockIdx.x * 64;
  size_t bhs = (size_t)(blockIdx.z*H_ + blockIdx.y) * LP_ * HD_;
  const u16* src = vh + bhs;
  u16* dst = vhT + bhs;
  int tid = threadIdx.x;
  #pragma unroll
  for (int it=0; it<2; ++it){
    int idx = it*256 + tid;                // 0..511
    int row = idx >> 3, ch = (idx & 7)*8;
    uint4 d4; d4.x=0u; d4.y=0u; d4.z=0u; d4.w=0u;
    if (ll0 + row < L_) d4 = *(const uint4*)(src + (size_t)(ll0+row)*HD_ + ch);
    *(uint4*)&t[row][ch] = d4;
  }
  __syncthreads();
  #pragma unroll
  for (int it=0; it<2; ++it){
    int idx = it*256 + tid;
    int dd = idx >> 3, l8 = (idx & 7)*8;
    u16 vals[8];
    #pragma unroll
    for (int e=0;e<8;++e) vals[e] = t[l8+e][dd];
    *(uint4*)(dst + (size_t)dd*LP_ + ll0 + l8) = *(uint4*)vals;
  }
}

// ---------------- merged QKV GEMM: 3 x (128x128 MFMA, m97 staging, XCD swizzle) ----------------
__global__ __launch_bounds__(256) void gemm_qkv(
    const u16* __restrict__ Aq, const u16* __restrict__ Ak, const u16* __restrict__ Av,
    const u16* __restrict__ WTbase,
    const float* __restrict__ bq, const float* __restrict__ bk, const float* __restrict__ bv,
    u16* __restrict__ Dq, u16* __restrict__ Dk, u16* __restrict__ Dv)
{
  __shared__ __align__(16) u16 AsL[128*32];
  __shared__ __align__(16) u16 BsL[128*32];
  const int blk = blockIdx.x;
  const int which = blk / 912;
  const int inner = blk - which*912;
  const int x = inner & 7, g = inner >> 3;   // XCD-slot, work id
  const int n0 = (g % 6) * 128;
  const int m_idx = (g / 6) * 8 + x;
  if (m_idx >= 145) return;
  const int m0 = m_idx * 128;

  const u16* A  = (which==0)?Aq:(which==1)?Ak:Av;
  const u16* BT = WTbase + (size_t)which*768*768;
  const float* bias = (which==0)?bq:(which==1)?bk:bv;
  u16* Dst = (which==0)?Dq:(which==1)?Dk:Dv;

  const int tid = threadIdx.x;
  const int w = tid>>6, lane = tid&63, q = lane>>4, c = lane&15;
  const int wr = w>>1, wc = w&1;

  f32x4 acc[4][4];
  #pragma unroll
  for (int ai=0;ai<4;++ai)
    #pragma unroll
    for (int bi=0;bi<4;++bi){ f32x4 z = {0.f,0.f,0.f,0.f}; acc[ai][bi] = z; }

  for (int k0 = 0; k0 < 768; k0 += 32){
    __syncthreads();
    #pragma unroll
    for (int t2 = 0; t2 < 2; ++t2){
      int idx = t2*256 + tid;
      int row = idx >> 2, ch = idx & 3;
      int mrow = m0 + row; if (mrow > M_-1) mrow = M_-1;
      async16(A + (size_t)mrow*768 + k0 + ch*8, (char*)AsL + (size_t)(t2*256 + w*64)*16);
      async16(BT + (size_t)(n0 + row)*768 + k0 + ch*8, (char*)BsL + (size_t)(t2*256 + w*64)*16);
    }
    __syncthreads();

    bf16x8 af[4], bf2[4];
    #pragma unroll
    for (int ai=0;ai<4;++ai) af[ai]  = *(const bf16x8*)&AsL[(wr*64 + ai*16 + c)*32 + q*8];
    #pragma unroll
    for (int bi=0;bi<4;++bi) bf2[bi] = *(const bf16x8*)&BsL[(wc*64 + bi*16 + c)*32 + q*8];
    #pragma unroll
    for (int ai=0;ai<4;++ai)
      #pragma unroll
      for (int bi=0;bi<4;++bi)
        acc[ai][bi] = mfma_bf16(af[ai], bf2[bi], acc[ai][bi]);
  }

  #pragma unroll
  for (int ai=0;ai<4;++ai){
    #pragma unroll
    for (int r2=0;r2<4;++r2){
      int mrow = m0 + wr*64 + ai*16 + q*4 + r2;
      if (mrow >= M_) continue;
      int bb = mrow / L_;
      int ll = mrow - bb*L_;
      #pragma unroll
      for (int bi=0;bi<4;++bi){
        int col = n0 + wc*64 + bi*16 + c;
        float vv = acc[ai][bi][r2] + bias[col];
        int hh = col >> 6, dd = col & 63;
        Dst[(((size_t)(bb*H_ + hh)*LP_ + ll) << 6) + dd] = f2b(vv);
      }
    }
  }
}

// ---------------- output-projection GEMM (mode 3 of the old gemm_kernel) ----------------
__global__ __launch_bounds__(256) void gemm_kernel(
    const u16* __restrict__ A, const u16* __restrict__ BT,
    const float* __restrict__ bias, const float* __restrict__ resid,
    void* __restrict__ Dstv, int mode)
{
  __shared__ __align__(16) u16 AsL[128*32];
  __shared__ __align__(16) u16 BsL[128*32];
  const int blk = blockIdx.x;
  const int x = blk & 7, g = blk >> 3;       // XCD-slot, work id
  const int n0 = (g % 6) * 128;
  const int m_idx = (g / 6) * 8 + x;
  if (m_idx >= 145) return;
  const int m0 = m_idx * 128;

  const int tid = threadIdx.x;
  const int w = tid>>6, lane = tid&63, q = lane>>4, c = lane&15;
  const int wr = w>>1, wc = w&1;

  f32x4 acc[4][4];
  #pragma unroll
  for (int ai=0;ai<4;++ai)
    #pragma unroll
    for (int bi=0;bi<4;++bi){ f32x4 z = {0.f,0.f,0.f,0.f}; acc[ai][bi] = z; }

  for (int k0 = 0; k0 < 768; k0 += 32){
    __syncthreads();
    #pragma unroll
    for (int t2 = 0; t2 < 2; ++t2){
      int idx = t2*256 + tid;
      int row = idx >> 2, ch = idx & 3;
      int mrow = m0 + row; if (mrow > M_-1) mrow = M_-1;
      const u16* srcA;
      if (mode < 3) srcA = A + (size_t)mrow*768 + k0 + ch*8;
      else {
        int bb = mrow / L_, ll = mrow - bb*L_;
        int hh = k0 >> 6, dd = (k0 & 63) + ch*8;
        srcA = A + (((size_t)(bb*H_ + hh)*LP_ + ll) << 6) + dd;
      }
      async16(srcA, (char*)AsL + (size_t)(t2*256 + w*64)*16);
      async16(BT + (size_t)(n0 + row)*768 + k0 + ch*8, (char*)BsL + (size_t)(t2*256 + w*64)*16);
    }
    __syncthreads();

    bf16x8 af[4], bf2[4];
    #pragma unroll
    for (int ai=0;ai<4;++ai) af[ai]  = *(const bf16x8*)&AsL[(wr*64 + ai*16 + c)*32 + q*8];
    #pragma unroll
    for (int bi=0;bi<4;++bi) bf2[bi] = *(const bf16x8*)&BsL[(wc*64 + bi*16 + c)*32 + q*8];
    #pragma unroll
    for (int ai=0;ai<4;++ai)
      #pragma unroll
      for (int bi=0;bi<4;++bi)
        acc[ai][bi] = mfma_bf16(af[ai], bf2[bi], acc[ai][bi]);
  }

  // epilogue: C layout row = q*4+reg, col = lane&15 (m89)
  #pragma unroll
  for (int ai=0;ai<4;++ai){
    #pragma unroll
    for (int r2=0;r2<4;++r2){
      int mrow = m0 + wr*64 + ai*16 + q*4 + r2;
      if (mrow >= M_) continue;
      int bb = mrow / L_;
      int ll = mrow - bb*L_;
      #pragma unroll
      for (int bi=0;bi<4;++bi){
        int col = n0 + wc*64 + bi*16 + c;
        float vv = acc[ai][bi][r2] + bias[col];
        if (mode < 3){
          int hh = col >> 6, dd = col & 63;
          ((u16*)Dstv)[(((size_t)(bb*H_ + hh)*LP_ + ll) << 6) + dd] = f2b(vv);
        } else {
          size_t o2 = (size_t)mrow*768 + col;
          ((float*)Dstv)[o2] = vv + resid[o2];
        }
      }
    }
  }
}

// ---------------- fused attention, barrier-free, software-pipelined ----------------
// 256 thr (4 waves), each wave owns 16 Q rows of one (b,h); 19 x 32-col j-tiles.
// Per-wave LDS 5632 B:
//   region A [0,3328): pvhb u16[16][66] (setup) -> Ps0@0 / Ps1@1280 (loop) -> gvh f32[16][52] (end)
//   region B [3328,5632): bias_t u16[16][52] (loop) -> Wm u16[16][72] (end)
// Pipeline: iteration jt computes softmax(jt+1) into Ps[(jt+1)&1] while PV MFMAs
// consume Ps[jt&1]. Zero __syncthreads; compiler barrier per iteration.
__global__ __launch_bounds__(256) void attn_kernel(
    const u16* __restrict__ qh, const u16* __restrict__ kh, const u16* __restrict__ vhT,
    const u16* __restrict__ tabK, const u16* __restrict__ tabVT,
    const u16* __restrict__ ind,
    u16* __restrict__ oh)
{
  __shared__ __align__(16) char sb[4*5632];
  const int tid = threadIdx.x;
  const int w = tid>>6, lane = tid&63, q = lane>>4, c = lane&15;
  char* wb = sb + w*5632;
  u16*   pvhb  = (u16*)wb;               // [16][66] u16 (setup only)
  u16*   Ps0   = (u16*)wb;               // [16][40] u16 (loop)
  u16*   Ps1   = (u16*)(wb + 1280);      // [16][40] u16 (loop)
  float* gvh   = (float*)wb;             // [16][52] f32 (after loop)
  u16*   bias_t= (u16*)(wb + 3328);      // [16][52] u16 (loop)
  u16*   Wm    = (u16*)(wb + 3328);      // [16][72] u16 (after loop)

  // XCD-chunked work decode: 8 XCDs x 480 contiguous ids; qt fastest within chunk
  const int id = blockIdx.x;
  const int lin = (id & 7)*480 + (id >> 3);
  const int qt = lin % 10;
  const int hb = lin / 10;
  const int h = hb % 12, b = hb / 12;

  const int i0 = qt * 64;
  const size_t bh = (size_t)(b*H_ + h) * LP_ * HD_;
  const u16* qh_b = qh + bh;
  const u16* kh_b = kh + bh;
  const u16* vT_b = vhT + bh;            // [64][LP_]

  // Q fragments (A layout: m=lane&15, k=q*8+j)
  bf16x8 aq0 = *(const bf16x8*)(qh_b + (size_t)(i0 + w*16 + c)*HD_ + q*8);
  bf16x8 aq1 = *(const bf16x8*)(qh_b + (size_t)(i0 + w*16 + c)*HD_ + 32 + q*8);

  // pvhb[16 rows][bins 0..59] = Q . tabK^T via MFMA
  #pragma unroll
  for (int nt=0; nt<4; ++nt){
    bf16x8 tb0 = *(const bf16x8*)(tabK + (size_t)(nt*16+c)*64 + q*8);
    bf16x8 tb1 = *(const bf16x8*)(tabK + (size_t)(nt*16+c)*64 + 32 + q*8);
    f32x4 s = {0.f,0.f,0.f,0.f};
    s = mfma_bf16(aq0, tb0, s);
    s = mfma_bf16(aq1, tb1, s);
    int bin = nt*16 + c;
    if (bin < 60){
      #pragma unroll
      for (int r=0;r<4;++r) pvhb[(q*4+r)*66 + bin] = f2b(s[r]);
    }
  }
  lds_fence();

  // build separable gather tables: bias_t[row][g] = pv_row(g), bias_t[row][25+cb] = ph_row(cb)
  for (int o = lane; o < 16*50; o += 64){
    int row = o / 50, t = o - (o/50)*50;
    int ig = i0 + w*16 + row;
    const u16* src = pvhb + row*66;
    u16 val;
    if (ig == 0){
      val = src[t < 25 ? 0 : 30];
    } else {
      int im1 = ig - 1;
      int rr = im1 / 24, cc2 = im1 - (im1/24)*24;
      if (t < 25){
        if (t == 24) val = src[0];
        else { int d = t - rr;  d = d < -14 ? -14 : (d > 14 ? 14 : d); val = src[15 + d]; }
      } else {
        int cb = t - 25;
        if (cb == 24) val = src[30];
        else { int d = cb - cc2; d = d < -14 ? -14 : (d > 14 ? 14 : d); val = src[45 + d]; }
      }
    }
    bias_t[row*52 + t] = val;
  }
  lds_fence();   // pvhb dead; Ps0/Ps1 may now overlay it

  int ig_[4];
  #pragma unroll
  for (int r=0;r<4;++r) ig_[r] = i0 + w*16 + q*4 + r;

  const u16* btr = bias_t + (q*4)*52;

  // QK^T + softmax for tile jtx -> dst
  auto qk_softmax = [&](int jtx, u16* dst){
    int j0x = jtx * 32;
    #pragma unroll
    for (int sub=0; sub<2; ++sub){
      const u16* kr = kh_b + (size_t)(j0x + sub*16 + c)*HD_;
      bf16x8 bk0 = *(const bf16x8*)(kr + q*8);
      bf16x8 bk1 = *(const bf16x8*)(kr + 32 + q*8);
      f32x4 s4 = {0.f,0.f,0.f,0.f};
      __builtin_amdgcn_s_setprio(1);
      s4 = mfma_bf16(aq0, bk0, s4);
      s4 = mfma_bf16(aq1, bk1, s4);
      __builtin_amdgcn_s_setprio(0);

      int j  = j0x + sub*16 + c;
      bool jv = (j < L_);
      int jj = j - 1;
      int q24 = jj / 24;
      int gR  = (j==0) ? 24 : (q24 > 23 ? 23 : q24);
      int cbR = (j==0) ? 24 : (jj - q24*24);

      #pragma unroll
      for (int r=0;r<4;++r){
        float bias = b2f(btr[r*52 + gR]) + b2f(btr[r*52 + 25 + cbR]);
        float s = fmaf(s4[r], SCALE_, bias);
        s = fminf(fmaxf(s, -80.f), 30.f);           // NaN-proof clamp
        float p = jv ? __expf(s) : 0.f;             // no-max softmax
        __bf16 pb = (__bf16)p;
        u16 pu; __builtin_memcpy(&pu, &pb, 2);
        dst[(q*4+r)*40 + sub*16 + c] = pu;
      }
    }
  };

  f32x4 o4[4], hist[4];
  #pragma unroll
  for (int nt=0;nt<4;++nt){ f32x4 z = {0.f,0.f,0.f,0.f}; o4[nt] = z; hist[nt] = z; }

  // prologue: P(0) -> Ps0
  qk_softmax(0, Ps0);

  for (int jt = 0; jt < 19; ++jt){
    int j0 = jt * 32;
    // independent global loads for THIS tile's PV (hide under QK/softmax below)
    bf16x8 bvf[4];
    #pragma unroll
    for (int nt=0;nt<4;++nt)
      bvf[nt] = *(const bf16x8*)(vT_b + (size_t)(nt*16+c)*LP_ + j0 + q*8);
    uint4 bi_raw[4];
    #pragma unroll
    for (int nt=0;nt<4;++nt) bi_raw[nt] = ((const uint4*)ind)[(jt*4 + nt)*64 + lane];

    cbar();   // order prev iter's Ps[cur] writes vs this read (same-wave DS in-order)
    u16* Pc = (jt & 1) ? Ps1 : Ps0;
    bf16x8 ap = *(const bf16x8*)(Pc + c*40 + q*8);

    // pipeline: softmax for tile jt+1 into the other buffer
    if (jt < 18) qk_softmax(jt+1, (jt & 1) ? Ps0 : Ps1);

    // PV + histogram MFMAs for tile jt
    __builtin_amdgcn_s_setprio(1);
    #pragma unroll
    for (int nt=0;nt<4;++nt){
      o4[nt] = mfma_bf16(ap, bvf[nt], o4[nt]);
      bf16x8 bI = *(const bf16x8*)&bi_raw[nt];
      hist[nt] = mfma_bf16(ap, bI, hist[nt]);
    }
    __builtin_amdgcn_s_setprio(0);
  }

  lds_fence();   // drain all DS before overlaying Ps/bias_t with gvh/Wm

  // histogram C-regs -> gvh: local row=q*4+r, bin=nt*16+c (each cell one writer)
  #pragma unroll
  for (int nt=0;nt<4;++nt){
    int bin = nt*16 + c;
    if (bin < 50){
      #pragma unroll
      for (int r=0;r<4;++r)
        gvh[(size_t)(q*4 + r)*52 + bin] = hist[nt][r];
    }
  }
  lds_fence();

  // fold histograms into table-space weights Wm[16][72] bf16 (overlay bias_t)
  for (int o = lane; o < 16*72; o += 64) Wm[o] = 0;
  lds_fence();
  if (lane < 16){
    int ig = i0 + w*16 + lane;
    const float* gv = gvh + (size_t)lane*52;
    u16* wrp = Wm + lane*72;
    if (ig == 0){
      float sv=0.f, sh=0.f;
      for (int g2=0; g2<25; ++g2){ sv += gv[g2]; sh += gv[25+g2]; }
      wrp[0] = f2b(sv); wrp[30] = f2b(sh);
    } else {
      int rr = (ig-1)/24, cc2 = (ig-1) - ((ig-1)/24)*24;
      wrp[0]  = f2b(gv[24]);     // CLS -> table idx 0
      wrp[30] = f2b(gv[49]);
      for (int t=1; t<30; ++t){
        float sv = 0.f, sh = 0.f;
        if (t == 1){
          for (int g2=0; g2 <= rr-14  && g2 < 24; ++g2) sv += gv[g2];
          for (int c2=0; c2 <= cc2-14 && c2 < 24; ++c2) sh += gv[25+c2];
        } else if (t == 29){
          for (int g2 = (rr+14  < 0 ? 0 : rr+14 ); g2 < 24; ++g2) sv += gv[g2];
          for (int c2 = (cc2+14 < 0 ? 0 : cc2+14); c2 < 24; ++c2) sh += gv[25+c2];
        } else {
          int g2 = rr  + t - 15; if (g2 >= 0 && g2 < 24) sv = gv[g2];
          int c2 = cc2 + t - 15; if (c2 >= 0 && c2 < 24) sh = gv[25+c2];
        }
        wrp[t] = f2b(sv); wrp[30+t] = f2b(sh);
      }
    }
  }
  lds_fence();

  // rel-V term: o += W(16x64) @ TabV(64x64), TabV^T from global
  bf16x8 aw0 = *(const bf16x8*)(Wm + c*72 + q*8);
  bf16x8 aw1 = *(const bf16x8*)(Wm + c*72 + 32 + q*8);
  __builtin_amdgcn_s_setprio(1);
  #pragma unroll
  for (int nt=0;nt<4;++nt){
    bf16x8 bt0 = *(const bf16x8*)(tabVT + (size_t)(nt*16+c)*64 + q*8);
    bf16x8 bt1 = *(const bf16x8*)(tabVT + (size_t)(nt*16+c)*64 + 32 + q*8);
    o4[nt] = mfma_bf16(aw0, bt0, o4[nt]);
    o4[nt] = mfma_bf16(aw1, bt1, o4[nt]);
  }
  __builtin_amdgcn_s_setprio(0);

  // softmax denominator from histogram row sums (bins 0..24) + store
  u16* oh_b = oh + bh;
  #pragma unroll
  for (int r=0;r<4;++r){
    if (ig_[r] < L_){
      const float* gr = gvh + (size_t)(q*4 + r)*52;
      f32x4 a0 = *(const f32x4*)(gr);
      f32x4 a1 = *(const f32x4*)(gr+4);
      f32x4 a2 = *(const f32x4*)(gr+8);
      f32x4 a3 = *(const f32x4*)(gr+12);
      f32x4 a4 = *(const f32x4*)(gr+16);
      f32x4 a5 = *(const f32x4*)(gr+20);
      float lsum = (a0[0]+a0[1]+a0[2]+a0[3]) + (a1[0]+a1[1]+a1[2]+a1[3])
                 + (a2[0]+a2[1]+a2[2]+a2[3]) + (a3[0]+a3[1]+a3[2]+a3[3])
                 + (a4[0]+a4[1]+a4[2]+a4[3]) + (a5[0]+a5[1]+a5[2]+a5[3]) + gr[24];
      float inv = 1.f / lsum;
      #pragma unroll
      for (int nt=0;nt<4;++nt)
        oh_b[(size_t)ig_[r]*HD_ + nt*16 + c] = f2b(o4[nt][r] * inv);
    }
  }
}

// ---------------- launch ----------------
extern "C" void kernel_launch(void* const* d_in, const int* in_sizes, int n_in,
                              void* d_out, int out_size, void* d_ws, size_t ws_size,
                              hipStream_t stream)
{
  (void)in_sizes; (void)n_in; (void)out_size; (void)ws_size;
  const float* q_   = (const float*)d_in[0];
  const float* k_   = (const float*)d_in[1];
  const float* v_   = (const float*)d_in[2];
  const float* Wq_  = (const float*)d_in[3];
  const float* bq_  = (const float*)d_in[4];
  const float* Wk_  = (const float*)d_in[5];
  const float* bk_  = (const float*)d_in[6];
  const float* Wv_  = (const float*)d_in[7];
  const float* bv_  = (const float*)d_in[8];
  const float* Wp_  = (const float*)d_in[9];
  const float* bp_  = (const float*)d_in[10];
  const float* tvk_ = (const float*)d_in[11];
  const float* thk_ = (const float*)d_in[12];
  const float* tvv_ = (const float*)d_in[13];
  const float* thv_ = (const float*)d_in[14];

  char* ws = (char*)d_ws;
  const size_t szHead = (size_t)B_*H_*LP_*HD_*2;   // 31,457,280 B
  const size_t szQKV  = (size_t)M_*D_*2;           // 28,360,704 B
  u16* qh   = (u16*)(ws);
  u16* kh   = (u16*)(ws + szHead);
  u16* vh   = (u16*)(ws + 2*szHead);
  u16* oh   = (u16*)(ws + 3*szHead);   // doubles as q_bf before attn
  u16* q_bf = oh;
  u16* k_bf = (u16*)(ws + 4*szHead);
  u16* v_bf = (u16*)(ws + 4*szHead + szQKV);
  u16* vhT  = k_bf;                    // overlay: k_bf/v_bf dead after their GEMMs
  u16* WqT  = (u16*)(ws + 4*szHead + 2*szQKV);
  u16* WkT  = WqT + 768*768;
  u16* WvT  = WkT + 768*768;
  u16* WpT  = WvT + 768*768;
  u16* ind  = WpT + 768*768;           // 77,824 B
  u16* tabK  = ind + 19*4*64*8;        // 8,192 B
  u16* tabVT = tabK + 64*64;           // 8,192 B
  // total ~187.4 MB

  ind_setup<<<19, 256, 0, stream>>>(ind);
  tab_setup<<<16, 256, 0, stream>>>(tvk_, thk_, tvv_, thv_, tabK, tabVT);
  transpose768<<<dim3(24,24,4), 256, 0, stream>>>(Wq_, Wk_, Wv_, Wp_, WqT, WkT, WvT, WpT);
  cvt3_bf16<<<dim3((M_*D_/8 + 255)/256, 3), 256, 0, stream>>>(q_, k_, v_, q_bf, k_bf, v_bf);
  gemm_qkv<<<2736, 256, 0, stream>>>(q_bf, k_bf, v_bf, WqT, bq_, bk_, bv_, qh, kh, vh);
  vtr_kernel<<<dim3(10,12,32), 256, 0, stream>>>(vh, vhT);
  attn_kernel<<<3840, 256, 0, stream>>>(qh, kh, vhT, tabK, tabVT, ind, oh);
  gemm_kernel<<<912, 256, 0, stream>>>(oh, WpT, bp_, q_, d_out, 3);
}

// Round 4
// 784.458 us; speedup vs baseline: 1.5123x; 1.0103x over previous
//
#include <hip/hip_runtime.h>
#include <cstdint>

// ElasticMHA on MI355X (gfx950). Inputs/outputs FLOAT32; internals bf16 MFMA.
// R10: de-serialized attention j-loop. Root cause of flat R9: compiler deferred
//      the ap (Ps read) lgkmcnt wait to the PV MFMAs, which sit after the next
//      tile's Ps writes -> PV waited on the whole next softmax. Fixes:
//      (1) explicit lgkmcnt(0) right after the ap ds_read, BEFORE new DS writes;
//      (2) K fragments register-prefetched 2 tiles deep (no global loads inside
//          softmax); (3) all 12 independent global loads batched at iteration
//          top, V/ind first so PV's counted vmcnt wait excludes the K prefetch.
//      ind+tab setup merged into one launch. Rest as R9.

typedef unsigned short u16;
typedef unsigned int   u32;
typedef __attribute__((ext_vector_type(8))) __bf16 bf16x8;
typedef __attribute__((ext_vector_type(4))) float  f32x4;

#define B_   32
#define L_   577
#define D_   768
#define H_   12
#define HD_  64
#define LP_  640            // padded rows per (b,h): 10 Q-tiles of 64
#define M_   (B_*L_)        // 18464
#define SCALE_ 0.125f

__device__ __forceinline__ float b2f(u16 u){ u32 x = ((u32)u) << 16; float f; __builtin_memcpy(&f,&x,4); return f; }
__device__ __forceinline__ u16 f2b(float f){ u32 x; __builtin_memcpy(&x,&f,4); u32 r = (x + 0x7FFFu + ((x>>16)&1u)) >> 16; return (u16)r; }

__device__ __forceinline__ f32x4 mfma_bf16(bf16x8 a, bf16x8 b, f32x4 c){
  return __builtin_amdgcn_mfma_f32_16x16x32_bf16(a, b, c, 0, 0, 0);
}

// async global->LDS, 16B/lane; LDS dest = wave-uniform base + lane*16 (m97/m104)
__device__ __forceinline__ void async16(const void* g, void* l){
  __builtin_amdgcn_global_load_lds(
    (const __attribute__((address_space(1))) void*)g,
    (__attribute__((address_space(3))) void*)l,
    16, 0, 0);
}

__device__ __forceinline__ void lds_fence(){
  asm volatile("s_waitcnt lgkmcnt(0)" ::: "memory");
}
// compiler-only ordering (same-wave LDS ops execute in order on HW)
__device__ __forceinline__ void cbar(){
  asm volatile("" ::: "memory");
}

// ---------------- merged setup: indicator fragments + combined rel tables ----------------
// blocks 0..18: ind[jt][nt][lane][idx] indicator B-fragments (see R6 comment)
// blocks 19..34: tabK[bin][d] / tabVT[d][bin] bf16 tables
__global__ __launch_bounds__(256) void setup_kernel(
    const float* __restrict__ tvk, const float* __restrict__ thk,
    const float* __restrict__ tvv, const float* __restrict__ thv,
    u16* __restrict__ ind, u16* __restrict__ tabK, u16* __restrict__ tabVT)
{
  int bx = blockIdx.x;
  if (bx < 19){
    int jt = bx;
    int t  = threadIdx.x;
    int nt = t >> 6, lane = t & 63;
    int qq = lane >> 4, cc = lane & 15;
    int n = nt*16 + cc;
    u16 vals[8];
    #pragma unroll
    for (int idx = 0; idx < 8; ++idx){
      int j = jt*32 + qq*8 + idx;
      int bv, bhh;
      if (j == 0){ bv = 24; bhh = 24; }
      else { int jj = j-1; bv = jj/24; if (bv > 23) bv = 23; bhh = jj - (jj/24)*24; }
      bool one = (n < 25) ? (bv == n) : ((n < 50) ? (bhh == n-25) : false);
      vals[idx] = one ? (u16)0x3F80 : (u16)0;
    }
    *(uint4*)&ind[(size_t)((jt*4 + nt)*64 + lane)*8] = *(uint4*)vals;
  } else {
    int i = (bx-19)*256 + threadIdx.x;
    if (i >= 64*64) return;
    int r = i >> 6, col = i & 63;
    float kv = 0.f;
    if (r < 30)      kv = tvk[r*HD_ + col];
    else if (r < 60) kv = thk[(r-30)*HD_ + col];
    tabK[i] = f2b(kv);
    float vv = 0.f;                    // tabVT: r = d, col = bin
    if (col < 30)      vv = tvv[col*HD_ + r];
    else if (col < 60) vv = thv[(col-30)*HD_ + r];
    tabVT[i] = f2b(vv);
  }
}

// ---------------- q/k/v f32 -> bf16 cvt prepass ----------------
__global__ __launch_bounds__(256) void cvt3_bf16(
    const float* __restrict__ q, const float* __restrict__ k, const float* __restrict__ v,
    u16* __restrict__ dq, u16* __restrict__ dk, u16* __restrict__ dv)
{
  int z = blockIdx.y;
  const float* s = (z==0)?q:(z==1)?k:v;
  u16*         d = (z==0)?dq:(z==1)?dk:dv;
  int i = blockIdx.x*256 + threadIdx.x;          // uint4 (8 elem) index
  if (i >= (M_*D_)/8) return;
  const float4* s4 = (const float4*)s;
  float4 a = s4[2*i], b = s4[2*i+1];
  uint4 o;
  o.x = (u32)f2b(a.x) | ((u32)f2b(a.y)<<16);
  o.y = (u32)f2b(a.z) | ((u32)f2b(a.w)<<16);
  o.z = (u32)f2b(b.x) | ((u32)f2b(b.y)<<16);
  o.w = (u32)f2b(b.z) | ((u32)f2b(b.w)<<16);
  ((uint4*)d)[i] = o;
}

// ---------------- weight transpose+cvt: WT[n][k] = bf16(W[k][n]) ----------------
__global__ __launch_bounds__(256) void transpose768(
    const float* __restrict__ W0, const float* __restrict__ W1,
    const float* __restrict__ W2, const float* __restrict__ W3,
    u16* __restrict__ T0, u16* __restrict__ T1, u16* __restrict__ T2, u16* __restrict__ T3)
{
  __shared__ float t[32][33];
  int z = blockIdx.z;
  const float* W = (z==0)?W0:(z==1)?W1:(z==2)?W2:W3;
  u16*         T = (z==0)?T0:(z==1)?T1:(z==2)?T2:T3;
  int kb = blockIdx.x*32, nb = blockIdx.y*32;
  int tx = threadIdx.x & 31, ty = threadIdx.x >> 5;   // 32 x 8
  #pragma unroll
  for (int r=0;r<32;r+=8) t[ty+r][tx] = W[(size_t)(kb+ty+r)*768 + nb+tx];
  __syncthreads();
  #pragma unroll
  for (int r=0;r<32;r+=8) T[(size_t)(nb+ty+r)*768 + kb+tx] = f2b(t[tx][ty+r]);
}

// ---------------- V head-layout -> V^T [b,h,d(64)][j(LP)], pad rows zeroed ----------------
__global__ __launch_bounds__(256) void vtr_kernel(
    const u16* __restrict__ vh, u16* __restrict__ vhT)
{
  __shared__ __align__(16) u16 t[64][72];
  int ll0 = blockIdx.x * 64;
  size_t bhs = (size_t)(blockIdx.z*H_ + blockIdx.y) * LP_ * HD_;
  const u16* src = vh + bhs;
  u16* dst = vhT + bhs;
  int tid = threadIdx.x;
  #pragma unroll
  for (int it=0; it<2; ++it){
    int idx = it*256 + tid;                // 0..511
    int row = idx >> 3, ch = (idx & 7)*8;
    uint4 d4; d4.x=0u; d4.y=0u; d4.z=0u; d4.w=0u;
    if (ll0 + row < L_) d4 = *(const uint4*)(src + (size_t)(ll0+row)*HD_ + ch);
    *(uint4*)&t[row][ch] = d4;
  }
  __syncthreads();
  #pragma unroll
  for (int it=0; it<2; ++it){
    int idx = it*256 + tid;
    int dd = idx >> 3, l8 = (idx & 7)*8;
    u16 vals[8];
    #pragma unroll
    for (int e=0;e<8;++e) vals[e] = t[l8+e][dd];
    *(uint4*)(dst + (size_t)dd*LP_ + ll0 + l8) = *(uint4*)vals;
  }
}

// ---------------- merged QKV GEMM: 3 x (128x128 MFMA, m97 staging, XCD swizzle) ----------------
__global__ __launch_bounds__(256) void gemm_qkv(
    const u16* __restrict__ Aq, const u16* __restrict__ Ak, const u16* __restrict__ Av,
    const u16* __restrict__ WTbase,
    const float* __restrict__ bq, const float* __restrict__ bk, const float* __restrict__ bv,
    u16* __restrict__ Dq, u16* __restrict__ Dk, u16* __restrict__ Dv)
{
  __shared__ __align__(16) u16 AsL[128*32];
  __shared__ __align__(16) u16 BsL[128*32];
  const int blk = blockIdx.x;
  const int which = blk / 912;
  const int inner = blk - which*912;
  const int x = inner & 7, g = inner >> 3;   // XCD-slot, work id
  const int n0 = (g % 6) * 128;
  const int m_idx = (g / 6) * 8 + x;
  if (m_idx >= 145) return;
  const int m0 = m_idx * 128;

  const u16* A  = (which==0)?Aq:(which==1)?Ak:Av;
  const u16* BT = WTbase + (size_t)which*768*768;
  const float* bias = (which==0)?bq:(which==1)?bk:bv;
  u16* Dst = (which==0)?Dq:(which==1)?Dk:Dv;

  const int tid = threadIdx.x;
  const int w = tid>>6, lane = tid&63, q = lane>>4, c = lane&15;
  const int wr = w>>1, wc = w&1;

  f32x4 acc[4][4];
  #pragma unroll
  for (int ai=0;ai<4;++ai)
    #pragma unroll
    for (int bi=0;bi<4;++bi){ f32x4 z = {0.f,0.f,0.f,0.f}; acc[ai][bi] = z; }

  for (int k0 = 0; k0 < 768; k0 += 32){
    __syncthreads();
    #pragma unroll
    for (int t2 = 0; t2 < 2; ++t2){
      int idx = t2*256 + tid;
      int row = idx >> 2, ch = idx & 3;
      int mrow = m0 + row; if (mrow > M_-1) mrow = M_-1;
      async16(A + (size_t)mrow*768 + k0 + ch*8, (char*)AsL + (size_t)(t2*256 + w*64)*16);
      async16(BT + (size_t)(n0 + row)*768 + k0 + ch*8, (char*)BsL + (size_t)(t2*256 + w*64)*16);
    }
    __syncthreads();

    bf16x8 af[4], bf2[4];
    #pragma unroll
    for (int ai=0;ai<4;++ai) af[ai]  = *(const bf16x8*)&AsL[(wr*64 + ai*16 + c)*32 + q*8];
    #pragma unroll
    for (int bi=0;bi<4;++bi) bf2[bi] = *(const bf16x8*)&BsL[(wc*64 + bi*16 + c)*32 + q*8];
    #pragma unroll
    for (int ai=0;ai<4;++ai)
      #pragma unroll
      for (int bi=0;bi<4;++bi)
        acc[ai][bi] = mfma_bf16(af[ai], bf2[bi], acc[ai][bi]);
  }

  #pragma unroll
  for (int ai=0;ai<4;++ai){
    #pragma unroll
    for (int r2=0;r2<4;++r2){
      int mrow = m0 + wr*64 + ai*16 + q*4 + r2;
      if (mrow >= M_) continue;
      int bb = mrow / L_;
      int ll = mrow - bb*L_;
      #pragma unroll
      for (int bi=0;bi<4;++bi){
        int col = n0 + wc*64 + bi*16 + c;
        float vv = acc[ai][bi][r2] + bias[col];
        int hh = col >> 6, dd = col & 63;
        Dst[(((size_t)(bb*H_ + hh)*LP_ + ll) << 6) + dd] = f2b(vv);
      }
    }
  }
}

// ---------------- output-projection GEMM ----------------
__global__ __launch_bounds__(256) void gemm_kernel(
    const u16* __restrict__ A, const u16* __restrict__ BT,
    const float* __restrict__ bias, const float* __restrict__ resid,
    void* __restrict__ Dstv, int mode)
{
  __shared__ __align__(16) u16 AsL[128*32];
  __shared__ __align__(16) u16 BsL[128*32];
  const int blk = blockIdx.x;
  const int x = blk & 7, g = blk >> 3;       // XCD-slot, work id
  const int n0 = (g % 6) * 128;
  const int m_idx = (g / 6) * 8 + x;
  if (m_idx >= 145) return;
  const int m0 = m_idx * 128;

  const int tid = threadIdx.x;
  const int w = tid>>6, lane = tid&63, q = lane>>4, c = lane&15;
  const int wr = w>>1, wc = w&1;

  f32x4 acc[4][4];
  #pragma unroll
  for (int ai=0;ai<4;++ai)
    #pragma unroll
    for (int bi=0;bi<4;++bi){ f32x4 z = {0.f,0.f,0.f,0.f}; acc[ai][bi] = z; }

  for (int k0 = 0; k0 < 768; k0 += 32){
    __syncthreads();
    #pragma unroll
    for (int t2 = 0; t2 < 2; ++t2){
      int idx = t2*256 + tid;
      int row = idx >> 2, ch = idx & 3;
      int mrow = m0 + row; if (mrow > M_-1) mrow = M_-1;
      const u16* srcA;
      if (mode < 3) srcA = A + (size_t)mrow*768 + k0 + ch*8;
      else {
        int bb = mrow / L_, ll = mrow - bb*L_;
        int hh = k0 >> 6, dd = (k0 & 63) + ch*8;
        srcA = A + (((size_t)(bb*H_ + hh)*LP_ + ll) << 6) + dd;
      }
      async16(srcA, (char*)AsL + (size_t)(t2*256 + w*64)*16);
      async16(BT + (size_t)(n0 + row)*768 + k0 + ch*8, (char*)BsL + (size_t)(t2*256 + w*64)*16);
    }
    __syncthreads();

    bf16x8 af[4], bf2[4];
    #pragma unroll
    for (int ai=0;ai<4;++ai) af[ai]  = *(const bf16x8*)&AsL[(wr*64 + ai*16 + c)*32 + q*8];
    #pragma unroll
    for (int bi=0;bi<4;++bi) bf2[bi] = *(const bf16x8*)&BsL[(wc*64 + bi*16 + c)*32 + q*8];
    #pragma unroll
    for (int ai=0;ai<4;++ai)
      #pragma unroll
      for (int bi=0;bi<4;++bi)
        acc[ai][bi] = mfma_bf16(af[ai], bf2[bi], acc[ai][bi]);
  }

  // epilogue: C layout row = q*4+reg, col = lane&15 (m89)
  #pragma unroll
  for (int ai=0;ai<4;++ai){
    #pragma unroll
    for (int r2=0;r2<4;++r2){
      int mrow = m0 + wr*64 + ai*16 + q*4 + r2;
      if (mrow >= M_) continue;
      int bb = mrow / L_;
      int ll = mrow - bb*L_;
      #pragma unroll
      for (int bi=0;bi<4;++bi){
        int col = n0 + wc*64 + bi*16 + c;
        float vv = acc[ai][bi][r2] + bias[col];
        if (mode < 3){
          int hh = col >> 6, dd = col & 63;
          ((u16*)Dstv)[(((size_t)(bb*H_ + hh)*LP_ + ll) << 6) + dd] = f2b(vv);
        } else {
          size_t o2 = (size_t)mrow*768 + col;
          ((float*)Dstv)[o2] = vv + resid[o2];
        }
      }
    }
  }
}

// ---------------- fused attention, barrier-free, register-pipelined ----------------
// 256 thr (4 waves), each wave owns 16 Q rows of one (b,h); 19 x 32-col j-tiles.
// Per-wave LDS 5632 B:
//   region A [0,3328): pvhb u16[16][66] (setup) -> Ps0@0 / Ps1@1280 (loop) -> gvh f32[16][52] (end)
//   region B [3328,5632): bias_t u16[16][52] (loop) -> Wm u16[16][72] (end)
// Iteration jt: batch-issue {V(jt), ind(jt), K(jt+2)}; ap=ds_read(Ps[cur]) with
// EARLY lgkmcnt(0) (before any new DS writes); softmax(jt+1) from kf_cur regs
// (no global loads inside); PV MFMAs carry only a counted vmcnt for V/ind.
__global__ __launch_bounds__(256) void attn_kernel(
    const u16* __restrict__ qh, const u16* __restrict__ kh, const u16* __restrict__ vhT,
    const u16* __restrict__ tabK, const u16* __restrict__ tabVT,
    const u16* __restrict__ ind,
    u16* __restrict__ oh)
{
  __shared__ __align__(16) char sb[4*5632];
  const int tid = threadIdx.x;
  const int w = tid>>6, lane = tid&63, q = lane>>4, c = lane&15;
  char* wb = sb + w*5632;
  u16*   pvhb  = (u16*)wb;               // [16][66] u16 (setup only)
  u16*   Ps0   = (u16*)wb;               // [16][40] u16 (loop)
  u16*   Ps1   = (u16*)(wb + 1280);      // [16][40] u16 (loop)
  float* gvh   = (float*)wb;             // [16][52] f32 (after loop)
  u16*   bias_t= (u16*)(wb + 3328);      // [16][52] u16 (loop)
  u16*   Wm    = (u16*)(wb + 3328);      // [16][72] u16 (after loop)

  // XCD-chunked work decode: 8 XCDs x 480 contiguous ids; qt fastest within chunk
  const int id = blockIdx.x;
  const int lin = (id & 7)*480 + (id >> 3);
  const int qt = lin % 10;
  const int hb = lin / 10;
  const int h = hb % 12, b = hb / 12;

  const int i0 = qt * 64;
  const size_t bh = (size_t)(b*H_ + h) * LP_ * HD_;
  const u16* qh_b = qh + bh;
  const u16* kh_b = kh + bh;
  const u16* vT_b = vhT + bh;            // [64][LP_]

  // Q fragments (A layout: m=lane&15, k=q*8+j)
  bf16x8 aq0 = *(const bf16x8*)(qh_b + (size_t)(i0 + w*16 + c)*HD_ + q*8);
  bf16x8 aq1 = *(const bf16x8*)(qh_b + (size_t)(i0 + w*16 + c)*HD_ + 32 + q*8);

  // pvhb[16 rows][bins 0..59] = Q . tabK^T via MFMA
  #pragma unroll
  for (int nt=0; nt<4; ++nt){
    bf16x8 tb0 = *(const bf16x8*)(tabK + (size_t)(nt*16+c)*64 + q*8);
    bf16x8 tb1 = *(const bf16x8*)(tabK + (size_t)(nt*16+c)*64 + 32 + q*8);
    f32x4 s = {0.f,0.f,0.f,0.f};
    s = mfma_bf16(aq0, tb0, s);
    s = mfma_bf16(aq1, tb1, s);
    int bin = nt*16 + c;
    if (bin < 60){
      #pragma unroll
      for (int r=0;r<4;++r) pvhb[(q*4+r)*66 + bin] = f2b(s[r]);
    }
  }
  lds_fence();

  // build separable gather tables: bias_t[row][g] = pv_row(g), bias_t[row][25+cb] = ph_row(cb)
  for (int o = lane; o < 16*50; o += 64){
    int row = o / 50, t = o - (o/50)*50;
    int ig = i0 + w*16 + row;
    const u16* src = pvhb + row*66;
    u16 val;
    if (ig == 0){
      val = src[t < 25 ? 0 : 30];
    } else {
      int im1 = ig - 1;
      int rr = im1 / 24, cc2 = im1 - (im1/24)*24;
      if (t < 25){
        if (t == 24) val = src[0];
        else { int d = t - rr;  d = d < -14 ? -14 : (d > 14 ? 14 : d); val = src[15 + d]; }
      } else {
        int cb = t - 25;
        if (cb == 24) val = src[30];
        else { int d = cb - cc2; d = d < -14 ? -14 : (d > 14 ? 14 : d); val = src[45 + d]; }
      }
    }
    bias_t[row*52 + t] = val;
  }
  lds_fence();   // pvhb dead; Ps0/Ps1 may now overlay it

  int ig_[4];
  #pragma unroll
  for (int r=0;r<4;++r) ig_[r] = i0 + w*16 + q*4 + r;

  const u16* btr = bias_t + (q*4)*52;

  // K fragment loader (tile jtx -> 4 regs)
  auto load_kf = [&](int jtx, bf16x8* kf){
    const u16* kr0 = kh_b + (size_t)(jtx*32 + c)*HD_;
    const u16* kr1 = kh_b + (size_t)(jtx*32 + 16 + c)*HD_;
    kf[0] = *(const bf16x8*)(kr0 + q*8);
    kf[1] = *(const bf16x8*)(kr0 + 32 + q*8);
    kf[2] = *(const bf16x8*)(kr1 + q*8);
    kf[3] = *(const bf16x8*)(kr1 + 32 + q*8);
  };

  // QK^T + softmax for tile jtx from preloaded K regs -> dst (no global loads)
  auto qk_softmax = [&](int jtx, const bf16x8* kf, u16* dst){
    int j0x = jtx * 32;
    #pragma unroll
    for (int sub=0; sub<2; ++sub){
      f32x4 s4 = {0.f,0.f,0.f,0.f};
      __builtin_amdgcn_s_setprio(1);
      s4 = mfma_bf16(aq0, kf[2*sub], s4);
      s4 = mfma_bf16(aq1, kf[2*sub+1], s4);
      __builtin_amdgcn_s_setprio(0);

      int j  = j0x + sub*16 + c;
      bool jv = (j < L_);
      int jj = j - 1;
      int q24 = jj / 24;
      int gR  = (j==0) ? 24 : (q24 > 23 ? 23 : q24);
      int cbR = (j==0) ? 24 : (jj - q24*24);

      #pragma unroll
      for (int r=0;r<4;++r){
        float bias = b2f(btr[r*52 + gR]) + b2f(btr[r*52 + 25 + cbR]);
        float s = fmaf(s4[r], SCALE_, bias);
        s = fminf(fmaxf(s, -80.f), 30.f);           // NaN-proof clamp
        float p = jv ? __expf(s) : 0.f;             // no-max softmax
        __bf16 pb = (__bf16)p;
        u16 pu; __builtin_memcpy(&pu, &pb, 2);
        dst[(q*4+r)*40 + sub*16 + c] = pu;
      }
    }
  };

  f32x4 o4[4], hist[4];
  #pragma unroll
  for (int nt=0;nt<4;++nt){ f32x4 z = {0.f,0.f,0.f,0.f}; o4[nt] = z; hist[nt] = z; }

  // prologue: softmax(0) -> Ps0; preload K(1) for iter 0's softmax(1)
  bf16x8 kf_cur[4], kf_nxt[4];
  load_kf(0, kf_cur);
  qk_softmax(0, kf_cur, Ps0);
  load_kf(1, kf_cur);

  for (int jt = 0; jt < 19; ++jt){
    int j0 = jt * 32;
    // batched independent loads: V/ind FIRST (consumed this iter), K(jt+2) LAST
    bf16x8 bvf[4];
    #pragma unroll
    for (int nt=0;nt<4;++nt)
      bvf[nt] = *(const bf16x8*)(vT_b + (size_t)(nt*16+c)*LP_ + j0 + q*8);
    uint4 bi_raw[4];
    #pragma unroll
    for (int nt=0;nt<4;++nt) bi_raw[nt] = ((const uint4*)ind)[(jt*4 + nt)*64 + lane];
    if (jt < 17) load_kf(jt+2, kf_nxt);

    cbar();   // pin: Ps read below stays after prior iter's Ps writes (TBAA)
    u16* Pc = (jt & 1) ? Ps1 : Ps0;
    bf16x8 ap = *(const bf16x8*)(Pc + c*40 + q*8);
    lds_fence();   // EARLY wait: ap resolved before any new DS writes are issued

    // softmax for tile jt+1 (register K, no global loads) into the other buffer
    if (jt < 18) qk_softmax(jt+1, kf_cur, (jt & 1) ? Ps0 : Ps1);

    // PV + histogram MFMAs for tile jt: only counted vmcnt on bvf/bi_raw
    __builtin_amdgcn_s_setprio(1);
    #pragma unroll
    for (int nt=0;nt<4;++nt){
      o4[nt] = mfma_bf16(ap, bvf[nt], o4[nt]);
      bf16x8 bI = *(const bf16x8*)&bi_raw[nt];
      hist[nt] = mfma_bf16(ap, bI, hist[nt]);
    }
    __builtin_amdgcn_s_setprio(0);

    #pragma unroll
    for (int e=0;e<4;++e) kf_cur[e] = kf_nxt[e];
  }

  lds_fence();   // drain all DS before overlaying Ps/bias_t with gvh/Wm

  // histogram C-regs -> gvh: local row=q*4+r, bin=nt*16+c (each cell one writer)
  #pragma unroll
  for (int nt=0;nt<4;++nt){
    int bin = nt*16 + c;
    if (bin < 50){
      #pragma unroll
      for (int r=0;r<4;++r)
        gvh[(size_t)(q*4 + r)*52 + bin] = hist[nt][r];
    }
  }
  lds_fence();

  // fold histograms into table-space weights Wm[16][72] bf16 (overlay bias_t)
  for (int o = lane; o < 16*72; o += 64) Wm[o] = 0;
  lds_fence();
  if (lane < 16){
    int ig = i0 + w*16 + lane;
    const float* gv = gvh + (size_t)lane*52;
    u16* wrp = Wm + lane*72;
    if (ig == 0){
      float sv=0.f, sh=0.f;
      for (int g2=0; g2<25; ++g2){ sv += gv[g2]; sh += gv[25+g2]; }
      wrp[0] = f2b(sv); wrp[30] = f2b(sh);
    } else {
      int rr = (ig-1)/24, cc2 = (ig-1) - ((ig-1)/24)*24;
      wrp[0]  = f2b(gv[24]);     // CLS -> table idx 0
      wrp[30] = f2b(gv[49]);
      for (int t=1; t<30; ++t){
        float sv = 0.f, sh = 0.f;
        if (t == 1){
          for (int g2=0; g2 <= rr-14  && g2 < 24; ++g2) sv += gv[g2];
          for (int c2=0; c2 <= cc2-14 && c2 < 24; ++c2) sh += gv[25+c2];
        } else if (t == 29){
          for (int g2 = (rr+14  < 0 ? 0 : rr+14 ); g2 < 24; ++g2) sv += gv[g2];
          for (int c2 = (cc2+14 < 0 ? 0 : cc2+14); c2 < 24; ++c2) sh += gv[25+c2];
        } else {
          int g2 = rr  + t - 15; if (g2 >= 0 && g2 < 24) sv = gv[g2];
          int c2 = cc2 + t - 15; if (c2 >= 0 && c2 < 24) sh = gv[25+c2];
        }
        wrp[t] = f2b(sv); wrp[30+t] = f2b(sh);
      }
    }
  }
  lds_fence();

  // rel-V term: o += W(16x64) @ TabV(64x64), TabV^T from global
  bf16x8 aw0 = *(const bf16x8*)(Wm + c*72 + q*8);
  bf16x8 aw1 = *(const bf16x8*)(Wm + c*72 + 32 + q*8);
  __builtin_amdgcn_s_setprio(1);
  #pragma unroll
  for (int nt=0;nt<4;++nt){
    bf16x8 bt0 = *(const bf16x8*)(tabVT + (size_t)(nt*16+c)*64 + q*8);
    bf16x8 bt1 = *(const bf16x8*)(tabVT + (size_t)(nt*16+c)*64 + 32 + q*8);
    o4[nt] = mfma_bf16(aw0, bt0, o4[nt]);
    o4[nt] = mfma_bf16(aw1, bt1, o4[nt]);
  }
  __builtin_amdgcn_s_setprio(0);

  // softmax denominator from histogram row sums (bins 0..24) + store
  u16* oh_b = oh + bh;
  #pragma unroll
  for (int r=0;r<4;++r){
    if (ig_[r] < L_){
      const float* gr = gvh + (size_t)(q*4 + r)*52;
      f32x4 a0 = *(const f32x4*)(gr);
      f32x4 a1 = *(const f32x4*)(gr+4);
      f32x4 a2 = *(const f32x4*)(gr+8);
      f32x4 a3 = *(const f32x4*)(gr+12);
      f32x4 a4 = *(const f32x4*)(gr+16);
      f32x4 a5 = *(const f32x4*)(gr+20);
      float lsum = (a0[0]+a0[1]+a0[2]+a0[3]) + (a1[0]+a1[1]+a1[2]+a1[3])
                 + (a2[0]+a2[1]+a2[2]+a2[3]) + (a3[0]+a3[1]+a3[2]+a3[3])
                 + (a4[0]+a4[1]+a4[2]+a4[3]) + (a5[0]+a5[1]+a5[2]+a5[3]) + gr[24];
      float inv = 1.f / lsum;
      #pragma unroll
      for (int nt=0;nt<4;++nt)
        oh_b[(size_t)ig_[r]*HD_ + nt*16 + c] = f2b(o4[nt][r] * inv);
    }
  }
}

// ---------------- launch ----------------
extern "C" void kernel_launch(void* const* d_in, const int* in_sizes, int n_in,
                              void* d_out, int out_size, void* d_ws, size_t ws_size,
                              hipStream_t stream)
{
  (void)in_sizes; (void)n_in; (void)out_size; (void)ws_size;
  const float* q_   = (const float*)d_in[0];
  const float* k_   = (const float*)d_in[1];
  const float* v_   = (const float*)d_in[2];
  const float* Wq_  = (const float*)d_in[3];
  const float* bq_  = (const float*)d_in[4];
  const float* Wk_  = (const float*)d_in[5];
  const float* bk_  = (const float*)d_in[6];
  const float* Wv_  = (const float*)d_in[7];
  const float* bv_  = (const float*)d_in[8];
  const float* Wp_  = (const float*)d_in[9];
  const float* bp_  = (const float*)d_in[10];
  const float* tvk_ = (const float*)d_in[11];
  const float* thk_ = (const float*)d_in[12];
  const float* tvv_ = (const float*)d_in[13];
  const float* thv_ = (const float*)d_in[14];

  char* ws = (char*)d_ws;
  const size_t szHead = (size_t)B_*H_*LP_*HD_*2;   // 31,457,280 B
  const size_t szQKV  = (size_t)M_*D_*2;           // 28,360,704 B
  u16* qh   = (u16*)(ws);
  u16* kh   = (u16*)(ws + szHead);
  u16* vh   = (u16*)(ws + 2*szHead);
  u16* oh   = (u16*)(ws + 3*szHead);   // doubles as q_bf before attn
  u16* q_bf = oh;
  u16* k_bf = (u16*)(ws + 4*szHead);
  u16* v_bf = (u16*)(ws + 4*szHead + szQKV);
  u16* vhT  = k_bf;                    // overlay: k_bf/v_bf dead after their GEMMs
  u16* WqT  = (u16*)(ws + 4*szHead + 2*szQKV);
  u16* WkT  = WqT + 768*768;
  u16* WvT  = WkT + 768*768;
  u16* WpT  = WvT + 768*768;
  u16* ind  = WpT + 768*768;           // 77,824 B
  u16* tabK  = ind + 19*4*64*8;        // 8,192 B
  u16* tabVT = tabK + 64*64;           // 8,192 B
  // total ~187.4 MB

  setup_kernel<<<35, 256, 0, stream>>>(tvk_, thk_, tvv_, thv_, ind, tabK, tabVT);
  transpose768<<<dim3(24,24,4), 256, 0, stream>>>(Wq_, Wk_, Wv_, Wp_, WqT, WkT, WvT, WpT);
  cvt3_bf16<<<dim3((M_*D_/8 + 255)/256, 3), 256, 0, stream>>>(q_, k_, v_, q_bf, k_bf, v_bf);
  gemm_qkv<<<2736, 256, 0, stream>>>(q_bf, k_bf, v_bf, WqT, bq_, bk_, bv_, qh, kh, vh);
  vtr_kernel<<<dim3(10,12,32), 256, 0, stream>>>(vh, vhT);
  attn_kernel<<<3840, 256, 0, stream>>>(qh, kh, vhT, tabK, tabVT, ind, oh);
  gemm_kernel<<<912, 256, 0, stream>>>(oh, WpT, bp_, q_, d_out, 3);
}